// Round 1
// baseline (3269.103 us; speedup 1.0000x reference)
//
#include <hip/hip_runtime.h>
#include <hip/hip_bf16.h>
#include <cstddef>

// ---------------------------------------------------------------------------
// Pixel2Mesh forward on MI355X. Round 0: correct fp32 implementation.
//   gconv(x) = x@W0 + A(x@W1) + b  ==> Y = x@[W0|W1] (GEMM, N=256), then
//   combine: h[v] = act(Y0[v] + sum_{u in N(v)} Y1[u] + b) (+ residual)
// Input gconv fuses projection+bilerp into the GEMM A-loader (no feats buf).
// ---------------------------------------------------------------------------

#define DIV_UP(a, b) (((a) + (b) - 1) / (b))

// ---------------- transpose (C,H,W) -> (H*W, C) ----------------------------
__global__ void transpose_chw(const float* __restrict__ in, float* __restrict__ out,
                              int C, int HW) {
    int idx = blockIdx.x * 256 + threadIdx.x;
    if (idx >= C * HW) return;
    int c = idx % C;
    int p = idx / C;
    out[(size_t)p * C + c] = in[(size_t)c * HW + p];
}

// ---------------- weight packing: B[k][j] = j<128 ? W0[k][j] : W1[k][j-128] -
__global__ void pack_in_kernel(const float* __restrict__ W0, const float* __restrict__ W1,
                               float* __restrict__ B, int Kin, int Kpad) {
    int idx = blockIdx.x * 256 + threadIdx.x;
    if (idx >= Kpad * 256) return;
    int k = idx >> 8, j = idx & 255;
    float v = 0.0f;
    if (k < Kin) v = (j < 128) ? W0[(size_t)k * 128 + j] : W1[(size_t)k * 128 + (j - 128)];
    B[idx] = v;
}

__global__ void pack_lay_kernel(const float* __restrict__ W0, const float* __restrict__ W1,
                                float* __restrict__ B) {
    int idx = blockIdx.x * 256 + threadIdx.x;  // 12*128*256
    int l = idx >> 15;
    int r = idx & 32767;
    int k = r >> 8, j = r & 255;
    float v = (j < 128) ? W0[(size_t)l * 16384 + k * 128 + j]
                        : W1[(size_t)l * 16384 + k * 128 + (j - 128)];
    B[idx] = v;
}

// ---------------- per-vertex projection + bilerp descriptors ----------------
__global__ void desc_kernel(const float* __restrict__ verts,
                            const float* __restrict__ cam_c, const float* __restrict__ cam_f,
                            const int* __restrict__ imgsz, int V,
                            int* __restrict__ sampi, float* __restrict__ sampw) {
    int v = blockIdx.x * 256 + threadIdx.x;
    if (v >= V) return;
    float X = verts[3 * v + 0], Yy = verts[3 * v + 1], Z = verts[3 * v + 2];
    float cx = cam_c[0], cy = cam_c[1], fx = cam_f[0], fy = cam_f[1];
    const float tz = 0.8f;
    float pz = Z + tz;
    float px = (fx * X + cx * Z + tz * cx) / pz;
    float py = (fy * Yy + cy * Z + tz * cy) / pz;
    float is = (float)imgsz[0];
    const int Ss[3] = {56, 28, 14};
    const int Cs[3] = {256, 512, 512};
#pragma unroll
    for (int m = 0; m < 3; ++m) {
        int S = Ss[m], C = Cs[m];
        float dim = (float)S;
        float x = px * dim / is;
        float y = py * dim / is;
        float x1 = floorf(x), y1 = floorf(y);
        float x2 = x1 + 1.0f, y2 = y1 + 1.0f;
        float smax = (float)(S - 1);
        int xi1 = (int)fminf(fmaxf(x1, 0.0f), smax);
        int xi2 = (int)fminf(fmaxf(x2, 0.0f), smax);
        int yi1 = (int)fminf(fmaxf(y1, 0.0f), smax);
        int yi2 = (int)fminf(fmaxf(y2, 0.0f), smax);
        int b = v * 12 + m * 4;
        sampi[b + 0] = (xi1 * S + yi1) * C;
        sampi[b + 1] = (xi1 * S + yi2) * C;
        sampi[b + 2] = (xi2 * S + yi1) * C;
        sampi[b + 3] = (xi2 * S + yi2) * C;
        sampw[b + 0] = (x2 - x) * (y2 - y);
        sampw[b + 1] = (x2 - x) * (y - y1);
        sampw[b + 2] = (x - x1) * (y2 - y);
        sampw[b + 3] = (x - x1) * (y - y1);
    }
}

// ---------------- rowptr from sorted src array ------------------------------
__global__ void rowptr_kernel(const int* __restrict__ src, int E, int V, int* __restrict__ rowptr) {
    int v = blockIdx.x * 256 + threadIdx.x;
    if (v > V) return;
    int lo = 0, hi = E;
    while (lo < hi) {
        int mid = (lo + hi) >> 1;
        if (src[mid] < v) lo = mid + 1; else hi = mid;
    }
    rowptr[v] = lo;
}

// ---------------- GEMM: Y[V x 256] = A[V x K] @ B[K x 256] ------------------
// BM=128, BN=128, BK=16, 256 threads, 8x8 microtile. grid=(2, ceil(V/128)).
// AMODE 0: plain A (lda given). AMODE 1: A generated from bilerp descriptors
// (k<1280) and shape features (k>=1280), zero padded to K.
struct GemmArgs {
    const float* A; int lda;
    const int* sampi; const float* sampw;
    const float* ft0; const float* ft1; const float* ft2;
    const float* shape; int sstride; int sdim;
    const float* B;
    float* Y;
    int V; int K;
};

template <int AMODE>
__global__ __launch_bounds__(256) void gemm_kernel(GemmArgs g) {
    __shared__ float As[16][128];
    __shared__ float Bs[16][140];
    int tid = threadIdx.x;
    int tx = tid & 15, ty = tid >> 4;
    int row0 = blockIdx.y * 128;
    int col0 = blockIdx.x * 128;
    float acc[8][8];
#pragma unroll
    for (int i = 0; i < 8; ++i)
#pragma unroll
        for (int j = 0; j < 8; ++j) acc[i][j] = 0.0f;

    for (int k0 = 0; k0 < g.K; k0 += 16) {
        __syncthreads();
        // ---- load A tile (128 rows x 16 k) ----
#pragma unroll
        for (int it = 0; it < 2; ++it) {
            int q = tid + it * 256;
            int row = q >> 2;
            int kc = (q & 3) << 2;
            int grow = row0 + row;
            float v0 = 0.f, v1 = 0.f, v2 = 0.f, v3 = 0.f;
            if (AMODE == 0) {
                if (grow < g.V) {
                    float4 f = *(const float4*)(g.A + (size_t)grow * g.lda + k0 + kc);
                    v0 = f.x; v1 = f.y; v2 = f.z; v3 = f.w;
                }
            } else {
                int kg = k0 + kc;
                if (grow < g.V) {
                    if (kg >= 1280) {
                        int j = kg - 1280;
                        const float* sp = g.shape + (size_t)grow * g.sstride;
                        v0 = (j + 0 < g.sdim) ? sp[j + 0] : 0.f;
                        v1 = (j + 1 < g.sdim) ? sp[j + 1] : 0.f;
                        v2 = (j + 2 < g.sdim) ? sp[j + 2] : 0.f;
                        v3 = (j + 3 < g.sdim) ? sp[j + 3] : 0.f;
                    } else {
                        int m, base;
                        const float* ft;
                        if (kg < 256)      { m = 0; base = 0;    ft = g.ft0; }
                        else if (kg < 768) { m = 1; base = 256;  ft = g.ft1; }
                        else               { m = 2; base = 768;  ft = g.ft2; }
                        const int* si = g.sampi + (size_t)grow * 12 + m * 4;
                        const float* sw = g.sampw + (size_t)grow * 12 + m * 4;
                        int c = kg - base;
                        float4 f11 = *(const float4*)(ft + si[0] + c);
                        float4 f12 = *(const float4*)(ft + si[1] + c);
                        float4 f21 = *(const float4*)(ft + si[2] + c);
                        float4 f22 = *(const float4*)(ft + si[3] + c);
                        float w11 = sw[0], w12 = sw[1], w21 = sw[2], w22 = sw[3];
                        v0 = w11 * f11.x + w12 * f12.x + w21 * f21.x + w22 * f22.x;
                        v1 = w11 * f11.y + w12 * f12.y + w21 * f21.y + w22 * f22.y;
                        v2 = w11 * f11.z + w12 * f12.z + w21 * f21.z + w22 * f22.z;
                        v3 = w11 * f11.w + w12 * f12.w + w21 * f21.w + w22 * f22.w;
                    }
                }
            }
            As[kc + 0][row] = v0;
            As[kc + 1][row] = v1;
            As[kc + 2][row] = v2;
            As[kc + 3][row] = v3;
        }
        // ---- load B tile (16 k x 128 cols), swizzled ----
#pragma unroll
        for (int it = 0; it < 2; ++it) {
            int q = tid + it * 256;
            int row = q >> 5;
            int c4 = (q & 31) << 2;
            float4 f = *(const float4*)(g.B + (size_t)(k0 + row) * 256 + col0 + c4);
            int phys = c4 + ((c4 >> 5) << 2);
            *(float4*)&Bs[row][phys] = f;
        }
        __syncthreads();
        // ---- compute ----
#pragma unroll
        for (int kk = 0; kk < 16; ++kk) {
            float a[8], b[8];
            *(float4*)&a[0] = *(const float4*)&As[kk][ty * 8];
            *(float4*)&a[4] = *(const float4*)&As[kk][ty * 8 + 4];
            int pl = tx * 8 + ((tx >> 2) << 2);
            *(float4*)&b[0] = *(const float4*)&Bs[kk][pl];
            *(float4*)&b[4] = *(const float4*)&Bs[kk][pl + 4];
#pragma unroll
            for (int i = 0; i < 8; ++i)
#pragma unroll
                for (int j = 0; j < 8; ++j) acc[i][j] += a[i] * b[j];
        }
    }
    // ---- store ----
#pragma unroll
    for (int i = 0; i < 8; ++i) {
        int grow = row0 + ty * 8 + i;
        if (grow < g.V) {
            float* yp = g.Y + (size_t)grow * 256 + col0 + tx * 8;
            *(float4*)yp = *(float4*)&acc[i][0];
            *(float4*)(yp + 4) = *(float4*)&acc[i][4];
        }
    }
}

// ---------------- combine: h = act(Y0 + agg(Y1) + b) [+ res] ---------------
__global__ __launch_bounds__(256) void combine_kernel(
    const float* __restrict__ Y, const float* __restrict__ bias,
    const int* __restrict__ rowptr, const int* __restrict__ dst,
    const float* __restrict__ h_in, float* __restrict__ h_out, int V, int mode) {
    int v = blockIdx.x * 2 + (threadIdx.x >> 7);
    int d = threadIdx.x & 127;
    if (v >= V) return;
    float val = Y[(size_t)v * 256 + d] + bias[d];
    int e0 = rowptr[v], e1 = rowptr[v + 1];
    for (int e = e0; e < e1; ++e) {
        int u = dst[e];
        val += Y[(size_t)u * 256 + 128 + d];
    }
    val = fmaxf(val, 0.0f);
    if (mode == 1) val += h_in[(size_t)v * 128 + d];
    h_out[(size_t)v * 128 + d] = val;
}

// ---------------- coord head: Yc[V x 6] = h @ [Wc0|Wc1] --------------------
__global__ void coordgemm_kernel(const float* __restrict__ h,
                                 const float* __restrict__ Wc0, const float* __restrict__ Wc1,
                                 int V, float* __restrict__ Yc) {
    int idx = blockIdx.x * 256 + threadIdx.x;
    if (idx >= V * 6) return;
    int v = idx / 6, j = idx % 6;
    const float* W = (j < 3) ? Wc0 : Wc1;
    int jj = (j < 3) ? j : j - 3;
    const float* hp = h + (size_t)v * 128;
    float acc = 0.0f;
#pragma unroll 8
    for (int k = 0; k < 128; ++k) acc += hp[k] * W[k * 3 + jj];
    Yc[idx] = acc;
}

__global__ void coordcombine_kernel(const float* __restrict__ Yc, const float* __restrict__ bc,
                                    const int* __restrict__ rowptr, const int* __restrict__ dst,
                                    int V, float* __restrict__ out) {
    int idx = blockIdx.x * 256 + threadIdx.x;
    if (idx >= V * 3) return;
    int v = idx / 3, j = idx % 3;
    float val = Yc[(size_t)v * 6 + j] + bc[j];
    int e0 = rowptr[v], e1 = rowptr[v + 1];
    for (int e = e0; e < e1; ++e) val += Yc[(size_t)dst[e] * 6 + 3 + j];
    out[(size_t)v * 3 + j] = val;
}

// ---------------- unpool -----------------------------------------------------
__global__ void unpool_kernel(float* __restrict__ verts, const float* __restrict__ h,
                              const int* __restrict__ mid, int V, int Nm,
                              float* __restrict__ featout) {
    int r = blockIdx.x;
    int t = threadIdx.x;
    if (r < V) {
        if (t < 128) featout[(size_t)r * 128 + t] = h[(size_t)r * 128 + t];
    } else {
        int i = r - V;
        int a = mid[2 * i], b = mid[2 * i + 1];
        if (t < 3) {
            verts[(size_t)r * 3 + t] = 0.5f * (verts[(size_t)a * 3 + t] + verts[(size_t)b * 3 + t]);
        } else if (t < 131) {
            int d = t - 3;
            featout[(size_t)r * 128 + d] =
                0.5f * (h[(size_t)a * 128 + d] + h[(size_t)b * 128 + d]);
        }
    }
}

// ---------------------------------------------------------------------------
extern "C" void kernel_launch(void* const* d_in, const int* in_sizes, int n_in,
                              void* d_out, int out_size, void* d_ws, size_t ws_size,
                              hipStream_t stream) {
    const float* f3 = (const float*)d_in[0];
    const float* f4 = (const float*)d_in[1];
    const float* f5 = (const float*)d_in[2];
    const float* verts0 = (const float*)d_in[3];
    const float* cam_c = (const float*)d_in[4];
    const float* cam_f = (const float*)d_in[5];
    const int* imgsz = (const int*)d_in[38];

    int V0 = in_sizes[3] / 3;
    int E[3] = {in_sizes[33] / 2, in_sizes[34] / 2, in_sizes[35] / 2};
    int Nm0 = in_sizes[36] / 2, Nm1 = in_sizes[37] / 2;
    int V1 = V0 + Nm0, V2 = V1 + Nm1;
    int Vs[3] = {V0, V1, V2};

    // ---- workspace layout (floats, 256B aligned) ----
    float* wsp = (float*)d_ws;
    auto alloc = [&](size_t n) {
        float* p = wsp;
        wsp += ((n + 63) & ~(size_t)63);
        return p;
    };
    float* ft0 = alloc((size_t)56 * 56 * 256);
    float* ft1 = alloc((size_t)28 * 28 * 512);
    float* ft2 = alloc((size_t)14 * 14 * 512);
    float* Bin = alloc((size_t)1408 * 256);
    float* Blay = alloc((size_t)12 * 128 * 256);
    float* Ybuf = alloc((size_t)V2 * 256);
    float* hA = alloc((size_t)V2 * 128);
    float* hB = alloc((size_t)V2 * 128);
    float* featbuf = alloc((size_t)V2 * 128);
    float* vertsbuf = alloc((size_t)V2 * 3);
    float* Yc = alloc((size_t)V2 * 6);
    int* sampi = (int*)alloc((size_t)V2 * 12);
    float* sampw = alloc((size_t)V2 * 12);
    int* rowptr = (int*)alloc((size_t)V2 + 1);

    // ---- transpose feature maps ----
    transpose_chw<<<DIV_UP(256 * 56 * 56, 256), 256, 0, stream>>>(f3, ft0, 256, 56 * 56);
    transpose_chw<<<DIV_UP(512 * 28 * 28, 256), 256, 0, stream>>>(f4, ft1, 512, 28 * 28);
    transpose_chw<<<DIV_UP(512 * 14 * 14, 256), 256, 0, stream>>>(f5, ft2, 512, 14 * 14);

    for (int si = 0; si < 3; ++si) {
        const float* Win0 = (const float*)d_in[6 + si * 9 + 0];
        const float* Win1 = (const float*)d_in[6 + si * 9 + 1];
        const float* bin = (const float*)d_in[6 + si * 9 + 2];
        const float* W0s = (const float*)d_in[6 + si * 9 + 3];
        const float* W1s = (const float*)d_in[6 + si * 9 + 4];
        const float* bs = (const float*)d_in[6 + si * 9 + 5];
        const float* Wc0 = (const float*)d_in[6 + si * 9 + 6];
        const float* Wc1 = (const float*)d_in[6 + si * 9 + 7];
        const float* bc = (const float*)d_in[6 + si * 9 + 8];
        const int* edges = (const int*)d_in[33 + si];
        int Ecur = E[si];
        const int* esrc = edges;
        const int* edst = edges + Ecur;
        int V = Vs[si];
        int indim = (si == 0) ? 1283 : 1408;
        int Kpad = (si == 0) ? 1296 : 1408;
        const float* vertsin = (si == 0) ? verts0 : vertsbuf;
        const float* shape = (si == 0) ? verts0 : featbuf;
        int sdim = (si == 0) ? 3 : 128;

        // pack weights
        pack_in_kernel<<<Kpad, 256, 0, stream>>>(Win0, Win1, Bin, indim, Kpad);
        pack_lay_kernel<<<12 * 128, 256, 0, stream>>>(W0s, W1s, Blay);
        // descriptors + rowptr
        desc_kernel<<<DIV_UP(V, 256), 256, 0, stream>>>(vertsin, cam_c, cam_f, imgsz, V,
                                                        sampi, sampw);
        rowptr_kernel<<<DIV_UP(V + 1, 256), 256, 0, stream>>>(esrc, Ecur, V, rowptr);

        // input gconv: gathered GEMM + combine
        {
            GemmArgs g = {};
            g.sampi = sampi; g.sampw = sampw;
            g.ft0 = ft0; g.ft1 = ft1; g.ft2 = ft2;
            g.shape = shape; g.sstride = sdim; g.sdim = sdim;
            g.B = Bin; g.Y = Ybuf; g.V = V; g.K = Kpad;
            dim3 grid(2, DIV_UP(V, 128));
            gemm_kernel<1><<<grid, 256, 0, stream>>>(g);
        }
        combine_kernel<<<DIV_UP(V, 2), 256, 0, stream>>>(Ybuf, bin, rowptr, edst, nullptr,
                                                         hA, V, 0);
        float* hcur = hA;
        float* hnext = hB;
        // 12 resnet layers
        for (int l = 0; l < 12; ++l) {
            GemmArgs g = {};
            g.A = hcur; g.lda = 128;
            g.B = Blay + (size_t)l * 128 * 256;
            g.Y = Ybuf; g.V = V; g.K = 128;
            dim3 grid(2, DIV_UP(V, 128));
            gemm_kernel<0><<<grid, 256, 0, stream>>>(g);
            combine_kernel<<<DIV_UP(V, 2), 256, 0, stream>>>(Ybuf, bs + (size_t)l * 128,
                                                             rowptr, edst, hcur, hnext, V, 1);
            float* t = hcur; hcur = hnext; hnext = t;
        }
        // coord head
        coordgemm_kernel<<<DIV_UP(V * 6, 256), 256, 0, stream>>>(hcur, Wc0, Wc1, V, Yc);
        float* ctarget = (si == 2) ? (float*)d_out : vertsbuf;
        coordcombine_kernel<<<DIV_UP(V * 3, 256), 256, 0, stream>>>(Yc, bc, rowptr, edst, V,
                                                                    ctarget);
        // unpool
        if (si < 2) {
            const int* mid = (const int*)d_in[36 + si];
            int Nm = (si == 0) ? Nm0 : Nm1;
            unpool_kernel<<<V + Nm, 192, 0, stream>>>(vertsbuf, hcur, mid, V, Nm, featbuf);
        }
    }
}

// Round 2
// 2196.084 us; speedup vs baseline: 1.4886x; 1.4886x over previous
//
#include <hip/hip_runtime.h>
#include <hip/hip_bf16.h>
#include <cstddef>
#include <cstdint>

#define DIV_UP(a, b) (((a) + (b) - 1) / (b))

typedef __attribute__((ext_vector_type(8))) short bf16x8v;
typedef __attribute__((ext_vector_type(4))) float f32x4v;

__device__ __forceinline__ unsigned short bf16_rn(float v) {
    unsigned int u = __float_as_uint(v);
    unsigned int r = (u + 0x7FFFu + ((u >> 16) & 1u)) >> 16;
    return (unsigned short)r;
}
__device__ __forceinline__ float bf16_f(unsigned short h) {
    return __uint_as_float(((unsigned int)h) << 16);
}
__device__ __forceinline__ void f2hl(float v, unsigned short& hi, unsigned short& lo) {
    hi = bf16_rn(v);
    float r = v - bf16_f(hi);
    lo = bf16_rn(r);
}

// ---------------- transpose (C,H,W) -> (H*W, C) ----------------------------
__global__ void transpose_chw(const float* __restrict__ in, float* __restrict__ out,
                              int C, int HW) {
    int idx = blockIdx.x * 256 + threadIdx.x;
    if (idx >= C * HW) return;
    int c = idx % C;
    int p = idx / C;
    out[(size_t)p * C + c] = in[(size_t)c * HW + p];
}

// ------------- pack per-map weight block for G precompute -------------------
// Bcomb_m[c][s*256+j] = (j<128 ? W0_s : W1_s)[(base+c)][j mod 128]
__global__ void pack_gb(const float* __restrict__ W00, const float* __restrict__ W01,
                        const float* __restrict__ W10, const float* __restrict__ W11,
                        const float* __restrict__ W20, const float* __restrict__ W21,
                        float* __restrict__ B, int base, int C) {
    int idx = blockIdx.x * 256 + threadIdx.x;
    if (idx >= C * 768) return;
    int c = idx / 768, r = idx % 768;
    int s = r >> 8, j = r & 255;
    const float* W0 = (s == 0) ? W00 : (s == 1) ? W10 : W20;
    const float* W1 = (s == 0) ? W01 : (s == 1) ? W11 : W21;
    float v = (j < 128) ? W0[(size_t)(base + c) * 128 + j]
                        : W1[(size_t)(base + c) * 128 + (j - 128)];
    B[idx] = v;
}

// ------------- pack layer weights, transposed, bf16 hi/lo -------------------
// Bt[l][n][k] : k<128 -> W0[l][k][n], else W1[l][k-128][n]
__global__ void pack_lay_bt(const float* __restrict__ W0, const float* __restrict__ W1,
                            unsigned short* __restrict__ Bhi, unsigned short* __restrict__ Blo) {
    int idx = blockIdx.x * 256 + threadIdx.x;  // 12*128*256
    int l = idx >> 15;
    int r = idx & 32767;
    int n = r >> 8, k = r & 255;
    float v = (k < 128) ? W0[(size_t)l * 16384 + k * 128 + n]
                        : W1[(size_t)l * 16384 + (k - 128) * 128 + n];
    unsigned short hi, lo;
    f2hl(v, hi, lo);
    Bhi[idx] = hi;
    Blo[idx] = lo;
}

// ------------- pack shape-input weights (rows 1280..1407), transposed -------
// Bt[n][k] = (n<128 ? Win0 : Win1)[(1280+k)][n mod 128]
__global__ void pack_sh_bt(const float* __restrict__ Win0, const float* __restrict__ Win1,
                           unsigned short* __restrict__ Bhi, unsigned short* __restrict__ Blo) {
    int idx = blockIdx.x * 256 + threadIdx.x;  // 256*128
    if (idx >= 256 * 128) return;
    int n = idx >> 7, k = idx & 127;
    float v = (n < 128) ? Win0[(size_t)(1280 + k) * 128 + n]
                        : Win1[(size_t)(1280 + k) * 128 + (n - 128)];
    unsigned short hi, lo;
    f2hl(v, hi, lo);
    Bhi[idx] = hi;
    Blo[idx] = lo;
}

// ---------------- per-vertex projection + bilerp descriptors ----------------
__global__ void desc_kernel(const float* __restrict__ verts,
                            const float* __restrict__ cam_c, const float* __restrict__ cam_f,
                            const int* __restrict__ imgsz, int V,
                            int* __restrict__ sampi, float* __restrict__ sampw) {
    int v = blockIdx.x * 256 + threadIdx.x;
    if (v >= V) return;
    float X = verts[3 * v + 0], Yy = verts[3 * v + 1], Z = verts[3 * v + 2];
    float cx = cam_c[0], cy = cam_c[1], fx = cam_f[0], fy = cam_f[1];
    const float tz = 0.8f;
    float pz = Z + tz;
    float px = (fx * X + cx * Z + tz * cx) / pz;
    float py = (fy * Yy + cy * Z + tz * cy) / pz;
    float is = (float)imgsz[0];
    const int Ss[3] = {56, 28, 14};
#pragma unroll
    for (int m = 0; m < 3; ++m) {
        int S = Ss[m];
        float dim = (float)S;
        float x = px * dim / is;
        float y = py * dim / is;
        float x1 = floorf(x), y1 = floorf(y);
        float x2 = x1 + 1.0f, y2 = y1 + 1.0f;
        float smax = (float)(S - 1);
        int xi1 = (int)fminf(fmaxf(x1, 0.0f), smax);
        int xi2 = (int)fminf(fmaxf(x2, 0.0f), smax);
        int yi1 = (int)fminf(fmaxf(y1, 0.0f), smax);
        int yi2 = (int)fminf(fmaxf(y2, 0.0f), smax);
        int b = v * 12 + m * 4;
        sampi[b + 0] = xi1 * S + yi1;   // pixel index into G_m
        sampi[b + 1] = xi1 * S + yi2;
        sampi[b + 2] = xi2 * S + yi1;
        sampi[b + 3] = xi2 * S + yi2;
        sampw[b + 0] = (x2 - x) * (y2 - y);
        sampw[b + 1] = (x2 - x) * (y - y1);
        sampw[b + 2] = (x - x1) * (y2 - y);
        sampw[b + 3] = (x - x1) * (y - y1);
    }
}

// ---------------- rowptr from sorted src array ------------------------------
__global__ void rowptr_kernel(const int* __restrict__ src, int E, int V, int* __restrict__ rowptr) {
    int v = blockIdx.x * 256 + threadIdx.x;
    if (v > V) return;
    int lo = 0, hi = E;
    while (lo < hi) {
        int mid = (lo + hi) >> 1;
        if (src[mid] < v) lo = mid + 1; else hi = mid;
    }
    rowptr[v] = lo;
}

// ---------------- fp32 vector GEMM (for G precompute only) ------------------
// Y[V x N] = A[V x K] @ B[K x N], BM=BN=128, BK=16, 8x8 microtile
__global__ __launch_bounds__(256) void vgemm(const float* __restrict__ A, int lda,
                                             const float* __restrict__ B, int N,
                                             float* __restrict__ Y, int V, int K) {
    __shared__ float As[16][128];
    __shared__ float Bs[16][140];
    int tid = threadIdx.x;
    int tx = tid & 15, ty = tid >> 4;
    int row0 = blockIdx.y * 128;
    int col0 = blockIdx.x * 128;
    float acc[8][8];
#pragma unroll
    for (int i = 0; i < 8; ++i)
#pragma unroll
        for (int j = 0; j < 8; ++j) acc[i][j] = 0.0f;

    for (int k0 = 0; k0 < K; k0 += 16) {
        __syncthreads();
#pragma unroll
        for (int it = 0; it < 2; ++it) {
            int q = tid + it * 256;
            int row = q >> 2;
            int kc = (q & 3) << 2;
            int grow = row0 + row;
            float4 f = make_float4(0.f, 0.f, 0.f, 0.f);
            if (grow < V) f = *(const float4*)(A + (size_t)grow * lda + k0 + kc);
            As[kc + 0][row] = f.x;
            As[kc + 1][row] = f.y;
            As[kc + 2][row] = f.z;
            As[kc + 3][row] = f.w;
        }
#pragma unroll
        for (int it = 0; it < 2; ++it) {
            int q = tid + it * 256;
            int row = q >> 5;
            int c4 = (q & 31) << 2;
            float4 f = *(const float4*)(B + (size_t)(k0 + row) * N + col0 + c4);
            int phys = c4 + ((c4 >> 5) << 2);
            *(float4*)&Bs[row][phys] = f;
        }
        __syncthreads();
#pragma unroll
        for (int kk = 0; kk < 16; ++kk) {
            float a[8], b[8];
            *(float4*)&a[0] = *(const float4*)&As[kk][ty * 8];
            *(float4*)&a[4] = *(const float4*)&As[kk][ty * 8 + 4];
            int pl = tx * 8 + ((tx >> 2) << 2);
            *(float4*)&b[0] = *(const float4*)&Bs[kk][pl];
            *(float4*)&b[4] = *(const float4*)&Bs[kk][pl + 4];
#pragma unroll
            for (int i = 0; i < 8; ++i)
#pragma unroll
                for (int j = 0; j < 8; ++j) acc[i][j] += a[i] * b[j];
        }
    }
#pragma unroll
    for (int i = 0; i < 8; ++i) {
        int grow = row0 + ty * 8 + i;
        if (grow < V) {
            float* yp = Y + (size_t)grow * N + col0 + tx * 8;
            *(float4*)yp = *(float4*)&acc[i][0];
            *(float4*)(yp + 4) = *(float4*)&acc[i][4];
        }
    }
}

// ---------------- input perceptual gather: Ybuf[v][0..255] ------------------
__global__ void gather_kernel(const float* __restrict__ G,
                              const int* __restrict__ sampi, const float* __restrict__ sampw,
                              float* __restrict__ Yb, int V, int stage,
                              const float* __restrict__ Win0, const float* __restrict__ Win1,
                              const float* __restrict__ shape) {
    int v = blockIdx.x;
    if (v >= V) return;
    int j = threadIdx.x;
    const float* G0 = G;
    const float* G1 = G + (size_t)3136 * 768;
    const float* G2 = G + (size_t)(3136 + 784) * 768;
    int b = v * 12;
    int co = stage * 256 + j;
    float acc = 0.0f;
#pragma unroll
    for (int s = 0; s < 4; ++s) acc += sampw[b + s] * G0[(size_t)sampi[b + s] * 768 + co];
#pragma unroll
    for (int s = 0; s < 4; ++s) acc += sampw[b + 4 + s] * G1[(size_t)sampi[b + 4 + s] * 768 + co];
#pragma unroll
    for (int s = 0; s < 4; ++s) acc += sampw[b + 8 + s] * G2[(size_t)sampi[b + 8 + s] * 768 + co];
    if (stage == 0) {
#pragma unroll
        for (int k = 0; k < 3; ++k) {
            float w = shape[v * 3 + k];
            float wv = (j < 128) ? Win0[(size_t)(1280 + k) * 128 + j]
                                 : Win1[(size_t)(1280 + k) * 128 + (j - 128)];
            acc += w * wv;
        }
    }
    Yb[(size_t)v * 256 + j] = acc;
}

// ---------------- input-layer combine: h = relu(Y0 + agg(Y1) + b) ----------
__global__ __launch_bounds__(256) void combine_in(
    const float* __restrict__ Y, const float* __restrict__ bias,
    const int* __restrict__ rowptr, const int* __restrict__ dst,
    float* __restrict__ hout, unsigned short* __restrict__ Ohi,
    unsigned short* __restrict__ Olo, int V) {
    int v = blockIdx.x * 2 + (threadIdx.x >> 7);
    int d = threadIdx.x & 127;
    if (v >= V) return;
    float val = Y[(size_t)v * 256 + d] + bias[d];
    int e0 = rowptr[v], e1 = rowptr[v + 1];
    for (int e = e0; e < e1; ++e) val += Y[(size_t)dst[e] * 256 + 128 + d];
    val = fmaxf(val, 0.0f);
    hout[(size_t)v * 128 + d] = val;
    unsigned short hi, lo;
    f2hl(val, hi, lo);
    Ohi[(size_t)v * 256 + d] = hi;
    Olo[(size_t)v * 256 + d] = lo;
}

// ---------------- pre-aggregation: Apack[v][128..255] = bf16(sum_nb h) ------
__global__ __launch_bounds__(256) void preagg(const float* __restrict__ h,
                                              const int* __restrict__ rowptr,
                                              const int* __restrict__ dst,
                                              unsigned short* __restrict__ Ohi,
                                              unsigned short* __restrict__ Olo, int V) {
    int v = blockIdx.x * 2 + (threadIdx.x >> 7);
    int d = threadIdx.x & 127;
    if (v >= V) return;
    float s = 0.0f;
    int e0 = rowptr[v], e1 = rowptr[v + 1];
    for (int e = e0; e < e1; ++e) s += h[(size_t)dst[e] * 128 + d];
    unsigned short hi, lo;
    f2hl(s, hi, lo);
    Ohi[(size_t)v * 256 + 128 + d] = hi;
    Olo[(size_t)v * 256 + 128 + d] = lo;
}

// ---------------- MFMA bf16x3 GEMM ------------------------------------------
// BM=64, BN=128, K-step 32, 256 threads (4 waves), wave computes 32x64.
// EPI 0: Yadd[row*256 + col0+col] += acc           (shape GEMM, N=256)
// EPI 1: fused layer epilogue (N=128): v=relu(acc+bias)+hprev; write hnext f32
//        and bf16 hi/lo into Opack columns [0,128).
struct MArgs {
    const unsigned short *Ahi, *Alo; int lda;
    const unsigned short *Bhi, *Blo; int K;  // Bt row-major [N][K]
    const float* bias; const float* hprev;
    float* hnext; unsigned short *Ohi, *Olo;
    float* Yadd;
    int V;
};

template <int EPI>
__global__ __launch_bounds__(256) void mgemm(MArgs g) {
    __shared__ unsigned short As_hi[64][40], As_lo[64][40];
    __shared__ unsigned short Bs_hi[128][40], Bs_lo[128][40];
    int tid = threadIdx.x;
    int row0 = blockIdx.y * 64;
    int col0 = blockIdx.x * 128;
    int l = tid & 63, wid = tid >> 6;
    int wr = wid & 1, wc = wid >> 1;
    int lw = l & 15, gg = l >> 4;
    f32x4v acc[2][4];
#pragma unroll
    for (int i = 0; i < 2; ++i)
#pragma unroll
        for (int j = 0; j < 4; ++j) acc[i][j] = (f32x4v){0.f, 0.f, 0.f, 0.f};

    int arow = tid >> 2, akoff = (tid & 3) * 8;
    for (int k0 = 0; k0 < g.K; k0 += 32) {
        __syncthreads();
        {
            int grow = row0 + arow;
            uint4 zh = make_uint4(0, 0, 0, 0), zl = make_uint4(0, 0, 0, 0);
            if (grow < g.V) {
                zh = *(const uint4*)(g.Ahi + (size_t)grow * g.lda + k0 + akoff);
                zl = *(const uint4*)(g.Alo + (size_t)grow * g.lda + k0 + akoff);
            }
            *(uint4*)&As_hi[arow][akoff] = zh;
            *(uint4*)&As_lo[arow][akoff] = zl;
        }
#pragma unroll
        for (int it = 0; it < 2; ++it) {
            int q = tid + it * 256;
            int n = q >> 2, koff = (q & 3) * 8;
            *(uint4*)&Bs_hi[n][koff] = *(const uint4*)(g.Bhi + (size_t)(col0 + n) * g.K + k0 + koff);
            *(uint4*)&Bs_lo[n][koff] = *(const uint4*)(g.Blo + (size_t)(col0 + n) * g.K + k0 + koff);
        }
        __syncthreads();
        bf16x8v ah[2], al[2], bh[4], bl[4];
#pragma unroll
        for (int mt = 0; mt < 2; ++mt) {
            int r = wr * 32 + mt * 16 + lw;
            ah[mt] = *(const bf16x8v*)&As_hi[r][gg * 8];
            al[mt] = *(const bf16x8v*)&As_lo[r][gg * 8];
        }
#pragma unroll
        for (int nt = 0; nt < 4; ++nt) {
            int c = wc * 64 + nt * 16 + lw;
            bh[nt] = *(const bf16x8v*)&Bs_hi[c][gg * 8];
            bl[nt] = *(const bf16x8v*)&Bs_lo[c][gg * 8];
        }
#pragma unroll
        for (int mt = 0; mt < 2; ++mt)
#pragma unroll
            for (int nt = 0; nt < 4; ++nt) {
                acc[mt][nt] = __builtin_amdgcn_mfma_f32_16x16x32_bf16(ah[mt], bh[nt], acc[mt][nt], 0, 0, 0);
                acc[mt][nt] = __builtin_amdgcn_mfma_f32_16x16x32_bf16(ah[mt], bl[nt], acc[mt][nt], 0, 0, 0);
                acc[mt][nt] = __builtin_amdgcn_mfma_f32_16x16x32_bf16(al[mt], bh[nt], acc[mt][nt], 0, 0, 0);
            }
    }
#pragma unroll
    for (int mt = 0; mt < 2; ++mt)
#pragma unroll
        for (int nt = 0; nt < 4; ++nt) {
            int colg = wc * 64 + nt * 16 + lw;
            float bv = (EPI == 1) ? g.bias[colg] : 0.0f;
#pragma unroll
            for (int r = 0; r < 4; ++r) {
                int rowg = row0 + wr * 32 + mt * 16 + gg * 4 + r;
                if (rowg >= g.V) continue;
                float v = acc[mt][nt][r];
                if (EPI == 0) {
                    size_t o = (size_t)rowg * 256 + col0 + colg;
                    g.Yadd[o] += v;
                } else {
                    v += bv;
                    v = fmaxf(v, 0.0f);
                    v += g.hprev[(size_t)rowg * 128 + colg];
                    g.hnext[(size_t)rowg * 128 + colg] = v;
                    unsigned short hi, lo;
                    f2hl(v, hi, lo);
                    g.Ohi[(size_t)rowg * 256 + colg] = hi;
                    g.Olo[(size_t)rowg * 256 + colg] = lo;
                }
            }
        }
}

// ---------------- coord head ------------------------------------------------
__global__ void coordgemm_kernel(const float* __restrict__ h,
                                 const float* __restrict__ Wc0, const float* __restrict__ Wc1,
                                 int V, float* __restrict__ Yc) {
    int idx = blockIdx.x * 256 + threadIdx.x;
    if (idx >= V * 6) return;
    int v = idx / 6, j = idx % 6;
    const float* W = (j < 3) ? Wc0 : Wc1;
    int jj = (j < 3) ? j : j - 3;
    const float* hp = h + (size_t)v * 128;
    float acc = 0.0f;
#pragma unroll 8
    for (int k = 0; k < 128; ++k) acc += hp[k] * W[k * 3 + jj];
    Yc[idx] = acc;
}

__global__ void coordcombine_kernel(const float* __restrict__ Yc, const float* __restrict__ bc,
                                    const int* __restrict__ rowptr, const int* __restrict__ dst,
                                    int V, float* __restrict__ out) {
    int idx = blockIdx.x * 256 + threadIdx.x;
    if (idx >= V * 3) return;
    int v = idx / 3, j = idx % 3;
    float val = Yc[(size_t)v * 6 + j] + bc[j];
    int e0 = rowptr[v], e1 = rowptr[v + 1];
    for (int e = e0; e < e1; ++e) val += Yc[(size_t)dst[e] * 6 + 3 + j];
    out[(size_t)v * 3 + j] = val;
}

// ---------------- unpool: verts midpoints + featpack hi/lo ------------------
__global__ void unpool_kernel(float* __restrict__ verts, const float* __restrict__ h,
                              const int* __restrict__ mid, int V, int Nm,
                              unsigned short* __restrict__ fphi, unsigned short* __restrict__ fplo) {
    int r = blockIdx.x;
    int t = threadIdx.x;  // 128
    if (r < V) {
        float v = h[(size_t)r * 128 + t];
        unsigned short hi, lo;
        f2hl(v, hi, lo);
        fphi[(size_t)r * 128 + t] = hi;
        fplo[(size_t)r * 128 + t] = lo;
    } else {
        int i = r - V;
        int a = mid[2 * i], b = mid[2 * i + 1];
        float v = 0.5f * (h[(size_t)a * 128 + t] + h[(size_t)b * 128 + t]);
        unsigned short hi, lo;
        f2hl(v, hi, lo);
        fphi[(size_t)r * 128 + t] = hi;
        fplo[(size_t)r * 128 + t] = lo;
        if (t < 3)
            verts[(size_t)r * 3 + t] = 0.5f * (verts[(size_t)a * 3 + t] + verts[(size_t)b * 3 + t]);
    }
}

// ---------------------------------------------------------------------------
extern "C" void kernel_launch(void* const* d_in, const int* in_sizes, int n_in,
                              void* d_out, int out_size, void* d_ws, size_t ws_size,
                              hipStream_t stream) {
    const float* f3 = (const float*)d_in[0];
    const float* f4 = (const float*)d_in[1];
    const float* f5 = (const float*)d_in[2];
    const float* verts0 = (const float*)d_in[3];
    const float* cam_c = (const float*)d_in[4];
    const float* cam_f = (const float*)d_in[5];
    const int* imgsz = (const int*)d_in[38];

    int V0 = in_sizes[3] / 3;
    int E[3] = {in_sizes[33] / 2, in_sizes[34] / 2, in_sizes[35] / 2};
    int Nm0 = in_sizes[36] / 2, Nm1 = in_sizes[37] / 2;
    int V1 = V0 + Nm0, V2 = V1 + Nm1;
    int Vs[3] = {V0, V1, V2};

    // ---- workspace (byte allocator, 256B aligned) ----
    char* wsp = (char*)d_ws;
    auto alloc = [&](size_t bytes) -> void* {
        void* p = (void*)wsp;
        wsp += (bytes + 255) & ~(size_t)255;
        return p;
    };
    float* ft0 = (float*)alloc((size_t)56 * 56 * 256 * 4);
    float* ft1 = (float*)alloc((size_t)28 * 28 * 512 * 4);
    float* ft2 = (float*)alloc((size_t)14 * 14 * 512 * 4);
    float* Bcomb0 = (float*)alloc((size_t)256 * 768 * 4);
    float* Bcomb1 = (float*)alloc((size_t)512 * 768 * 4);
    float* Bcomb2 = (float*)alloc((size_t)512 * 768 * 4);
    float* Gbuf = (float*)alloc((size_t)(3136 + 784 + 196) * 768 * 4);
    unsigned short* BtLhi = (unsigned short*)alloc((size_t)12 * 128 * 256 * 2);
    unsigned short* BtLlo = (unsigned short*)alloc((size_t)12 * 128 * 256 * 2);
    unsigned short* BtShi = (unsigned short*)alloc((size_t)256 * 128 * 2);
    unsigned short* BtSlo = (unsigned short*)alloc((size_t)256 * 128 * 2);
    float* Ybuf = (float*)alloc((size_t)V2 * 256 * 4);
    float* hA = (float*)alloc((size_t)V2 * 128 * 4);
    float* hB = (float*)alloc((size_t)V2 * 128 * 4);
    unsigned short* Aphi = (unsigned short*)alloc((size_t)V2 * 256 * 2);
    unsigned short* Aplo = (unsigned short*)alloc((size_t)V2 * 256 * 2);
    unsigned short* FPhi = (unsigned short*)alloc((size_t)V2 * 128 * 2);
    unsigned short* FPlo = (unsigned short*)alloc((size_t)V2 * 128 * 2);
    float* vertsbuf = (float*)alloc((size_t)V2 * 3 * 4);
    float* Yc = (float*)alloc((size_t)V2 * 6 * 4);
    int* sampi = (int*)alloc((size_t)V2 * 12 * 4);
    float* sampw = (float*)alloc((size_t)V2 * 12 * 4);
    int* rowptr = (int*)alloc(((size_t)V2 + 1) * 4);

    // ---- feature map transpose ----
    transpose_chw<<<DIV_UP(256 * 56 * 56, 256), 256, 0, stream>>>(f3, ft0, 256, 56 * 56);
    transpose_chw<<<DIV_UP(512 * 28 * 28, 256), 256, 0, stream>>>(f4, ft1, 512, 28 * 28);
    transpose_chw<<<DIV_UP(512 * 14 * 14, 256), 256, 0, stream>>>(f5, ft2, 512, 14 * 14);

    const float* W0s_[3] = {(const float*)d_in[6], (const float*)d_in[15], (const float*)d_in[24]};
    const float* W1s_[3] = {(const float*)d_in[7], (const float*)d_in[16], (const float*)d_in[25]};

    // ---- G precompute: G_m = ft_m @ Bcomb_m  (768 cols = 3 stages x 256) ----
    pack_gb<<<DIV_UP(256 * 768, 256), 256, 0, stream>>>(W0s_[0], W1s_[0], W0s_[1], W1s_[1],
                                                        W0s_[2], W1s_[2], Bcomb0, 0, 256);
    pack_gb<<<DIV_UP(512 * 768, 256), 256, 0, stream>>>(W0s_[0], W1s_[0], W0s_[1], W1s_[1],
                                                        W0s_[2], W1s_[2], Bcomb1, 256, 512);
    pack_gb<<<DIV_UP(512 * 768, 256), 256, 0, stream>>>(W0s_[0], W1s_[0], W0s_[1], W1s_[1],
                                                        W0s_[2], W1s_[2], Bcomb2, 768, 512);
    float* G0 = Gbuf;
    float* G1 = Gbuf + (size_t)3136 * 768;
    float* G2 = Gbuf + (size_t)(3136 + 784) * 768;
    {
        dim3 g0(6, DIV_UP(3136, 128));
        vgemm<<<g0, 256, 0, stream>>>(ft0, 256, Bcomb0, 768, G0, 3136, 256);
        dim3 g1(6, DIV_UP(784, 128));
        vgemm<<<g1, 256, 0, stream>>>(ft1, 512, Bcomb1, 768, G1, 784, 512);
        dim3 g2(6, DIV_UP(196, 128));
        vgemm<<<g2, 256, 0, stream>>>(ft2, 512, Bcomb2, 768, G2, 196, 512);
    }

    for (int si = 0; si < 3; ++si) {
        const float* Win0 = (const float*)d_in[6 + si * 9 + 0];
        const float* Win1 = (const float*)d_in[6 + si * 9 + 1];
        const float* bin = (const float*)d_in[6 + si * 9 + 2];
        const float* W0L = (const float*)d_in[6 + si * 9 + 3];
        const float* W1L = (const float*)d_in[6 + si * 9 + 4];
        const float* bs = (const float*)d_in[6 + si * 9 + 5];
        const float* Wc0 = (const float*)d_in[6 + si * 9 + 6];
        const float* Wc1 = (const float*)d_in[6 + si * 9 + 7];
        const float* bc = (const float*)d_in[6 + si * 9 + 8];
        const int* edges = (const int*)d_in[33 + si];
        int Ecur = E[si];
        const int* esrc = edges;
        const int* edst = edges + Ecur;
        int V = Vs[si];
        const float* vertsin = (si == 0) ? verts0 : vertsbuf;

        pack_lay_bt<<<12 * 128, 256, 0, stream>>>(W0L, W1L, BtLhi, BtLlo);
        if (si > 0) pack_sh_bt<<<128, 256, 0, stream>>>(Win0, Win1, BtShi, BtSlo);
        desc_kernel<<<DIV_UP(V, 256), 256, 0, stream>>>(vertsin, cam_c, cam_f, imgsz, V,
                                                        sampi, sampw);
        rowptr_kernel<<<DIV_UP(V + 1, 256), 256, 0, stream>>>(esrc, Ecur, V, rowptr);

        // input gconv: perceptual gather (+stage0 shape), then shape GEMM (si>0)
        gather_kernel<<<V, 256, 0, stream>>>(Gbuf, sampi, sampw, Ybuf, V, si, Win0, Win1,
                                             (si == 0) ? verts0 : nullptr);
        if (si > 0) {
            MArgs m = {};
            m.Ahi = FPhi; m.Alo = FPlo; m.lda = 128;
            m.Bhi = BtShi; m.Blo = BtSlo; m.K = 128;
            m.Yadd = Ybuf; m.V = V;
            dim3 grid(2, DIV_UP(V, 64));
            mgemm<0><<<grid, 256, 0, stream>>>(m);
        }
        combine_in<<<DIV_UP(V, 2), 256, 0, stream>>>(Ybuf, bin, rowptr, edst, hA, Aphi, Aplo, V);

        float* hcur = hA;
        float* hnext = hB;
        for (int ll = 0; ll < 12; ++ll) {
            preagg<<<DIV_UP(V, 2), 256, 0, stream>>>(hcur, rowptr, edst, Aphi, Aplo, V);
            MArgs m = {};
            m.Ahi = Aphi; m.Alo = Aplo; m.lda = 256;
            m.Bhi = BtLhi + (size_t)ll * 32768; m.Blo = BtLlo + (size_t)ll * 32768;
            m.K = 256;
            m.bias = bs + (size_t)ll * 128;
            m.hprev = hcur; m.hnext = hnext;
            m.Ohi = Aphi; m.Olo = Aplo;
            m.V = V;
            dim3 grid(1, DIV_UP(V, 64));
            mgemm<1><<<grid, 256, 0, stream>>>(m);
            float* t = hcur; hcur = hnext; hnext = t;
        }

        coordgemm_kernel<<<DIV_UP(V * 6, 256), 256, 0, stream>>>(hcur, Wc0, Wc1, V, Yc);
        float* ctarget = (si == 2) ? (float*)d_out : vertsbuf;
        coordcombine_kernel<<<DIV_UP(V * 3, 256), 256, 0, stream>>>(Yc, bc, rowptr, edst, V,
                                                                    ctarget);
        if (si < 2) {
            const int* mid = (const int*)d_in[36 + si];
            int Nm = (si == 0) ? Nm0 : Nm1;
            unpool_kernel<<<V + Nm, 128, 0, stream>>>(vertsbuf, hcur, mid, V, Nm, FPhi, FPlo);
        }
    }
}

// Round 3
// 1529.509 us; speedup vs baseline: 2.1374x; 1.4358x over previous
//
#include <hip/hip_runtime.h>
#include <hip/hip_bf16.h>
#include <cstddef>
#include <cstdint>

#define DIV_UP(a, b) (((a) + (b) - 1) / (b))

typedef __attribute__((ext_vector_type(8))) short bf16x8v;
typedef __attribute__((ext_vector_type(4))) float f32x4v;

__device__ __forceinline__ unsigned short bf16_rn(float v) {
    unsigned int u = __float_as_uint(v);
    unsigned int r = (u + 0x7FFFu + ((u >> 16) & 1u)) >> 16;
    return (unsigned short)r;
}
__device__ __forceinline__ float bf16_f(unsigned short h) {
    return __uint_as_float(((unsigned int)h) << 16);
}
__device__ __forceinline__ void f2hl(float v, unsigned short& hi, unsigned short& lo) {
    hi = bf16_rn(v);
    float r = v - bf16_f(hi);
    lo = bf16_rn(r);
}

// ---------------- transpose (C,H,W) f32 -> (H*W, C) bf16 hi/lo --------------
__global__ void transpose_hl(const float* __restrict__ in, unsigned short* __restrict__ ohi,
                             unsigned short* __restrict__ olo, int C, int HW) {
    int idx = blockIdx.x * 256 + threadIdx.x;
    if (idx >= C * HW) return;
    int c = idx % C;
    int p = idx / C;
    float v = in[(size_t)c * HW + p];
    unsigned short hi, lo;
    f2hl(v, hi, lo);
    ohi[(size_t)p * C + c] = hi;
    olo[(size_t)p * C + c] = lo;
}

// ------------- pack G-weights transposed: Bt[n=768][k=C] hi/lo --------------
// n -> stage s=n>>8, j=n&255; value = (j<128 ? W0_s : W1_s)[(base+k)][j&127]
__global__ void pack_gb_bt(const float* __restrict__ W00, const float* __restrict__ W01,
                           const float* __restrict__ W10, const float* __restrict__ W11,
                           const float* __restrict__ W20, const float* __restrict__ W21,
                           unsigned short* __restrict__ Bhi, unsigned short* __restrict__ Blo,
                           int base, int C) {
    int idx = blockIdx.x * 256 + threadIdx.x;
    if (idx >= 768 * C) return;
    int n = idx / C, k = idx % C;
    int s = n >> 8, j = n & 255;
    const float* W0 = (s == 0) ? W00 : (s == 1) ? W10 : W20;
    const float* W1 = (s == 0) ? W01 : (s == 1) ? W11 : W21;
    float v = (j < 128) ? W0[(size_t)(base + k) * 128 + j]
                        : W1[(size_t)(base + k) * 128 + (j - 128)];
    unsigned short hi, lo;
    f2hl(v, hi, lo);
    Bhi[idx] = hi;
    Blo[idx] = lo;
}

// ------------- pack layer weights, transposed, bf16 hi/lo -------------------
// Bt[l][n][k] : k<128 -> W0[l][k][n], else W1[l][k-128][n]
__global__ void pack_lay_bt(const float* __restrict__ W0, const float* __restrict__ W1,
                            unsigned short* __restrict__ Bhi, unsigned short* __restrict__ Blo) {
    int idx = blockIdx.x * 256 + threadIdx.x;  // 12*128*256
    int l = idx >> 15;
    int r = idx & 32767;
    int n = r >> 8, k = r & 255;
    float v = (k < 128) ? W0[(size_t)l * 16384 + k * 128 + n]
                        : W1[(size_t)l * 16384 + (k - 128) * 128 + n];
    unsigned short hi, lo;
    f2hl(v, hi, lo);
    Bhi[idx] = hi;
    Blo[idx] = lo;
}

// ------------- pack shape-input weights (rows 1280..1407), transposed -------
__global__ void pack_sh_bt(const float* __restrict__ Win0, const float* __restrict__ Win1,
                           unsigned short* __restrict__ Bhi, unsigned short* __restrict__ Blo) {
    int idx = blockIdx.x * 256 + threadIdx.x;  // 256*128
    if (idx >= 256 * 128) return;
    int n = idx >> 7, k = idx & 127;
    float v = (n < 128) ? Win0[(size_t)(1280 + k) * 128 + n]
                        : Win1[(size_t)(1280 + k) * 128 + (n - 128)];
    unsigned short hi, lo;
    f2hl(v, hi, lo);
    Bhi[idx] = hi;
    Blo[idx] = lo;
}

// ---------------- per-vertex projection + bilerp descriptors ----------------
__global__ void desc_kernel(const float* __restrict__ verts,
                            const float* __restrict__ cam_c, const float* __restrict__ cam_f,
                            const int* __restrict__ imgsz, int V,
                            int* __restrict__ sampi, float* __restrict__ sampw) {
    int v = blockIdx.x * 256 + threadIdx.x;
    if (v >= V) return;
    float X = verts[3 * v + 0], Yy = verts[3 * v + 1], Z = verts[3 * v + 2];
    float cx = cam_c[0], cy = cam_c[1], fx = cam_f[0], fy = cam_f[1];
    const float tz = 0.8f;
    float pz = Z + tz;
    float px = (fx * X + cx * Z + tz * cx) / pz;
    float py = (fy * Yy + cy * Z + tz * cy) / pz;
    float is = (float)imgsz[0];
    const int Ss[3] = {56, 28, 14};
#pragma unroll
    for (int m = 0; m < 3; ++m) {
        int S = Ss[m];
        float dim = (float)S;
        float x = px * dim / is;
        float y = py * dim / is;
        float x1 = floorf(x), y1 = floorf(y);
        float x2 = x1 + 1.0f, y2 = y1 + 1.0f;
        float smax = (float)(S - 1);
        int xi1 = (int)fminf(fmaxf(x1, 0.0f), smax);
        int xi2 = (int)fminf(fmaxf(x2, 0.0f), smax);
        int yi1 = (int)fminf(fmaxf(y1, 0.0f), smax);
        int yi2 = (int)fminf(fmaxf(y2, 0.0f), smax);
        int b = v * 12 + m * 4;
        sampi[b + 0] = xi1 * S + yi1;
        sampi[b + 1] = xi1 * S + yi2;
        sampi[b + 2] = xi2 * S + yi1;
        sampi[b + 3] = xi2 * S + yi2;
        sampw[b + 0] = (x2 - x) * (y2 - y);
        sampw[b + 1] = (x2 - x) * (y - y1);
        sampw[b + 2] = (x - x1) * (y2 - y);
        sampw[b + 3] = (x - x1) * (y - y1);
    }
}

// ---------------- rowptr from sorted src array ------------------------------
__global__ void rowptr_kernel(const int* __restrict__ src, int E, int V, int* __restrict__ rowptr) {
    int v = blockIdx.x * 256 + threadIdx.x;
    if (v > V) return;
    int lo = 0, hi = E;
    while (lo < hi) {
        int mid = (lo + hi) >> 1;
        if (src[mid] < v) lo = mid + 1; else hi = mid;
    }
    rowptr[v] = lo;
}

// ---------------- MFMA bf16x3 GEMM (shape GEMM + G precompute) --------------
// BM=64, BN=128, K-step 32, 256 threads (4 waves), wave computes 32x64.
// EPI 0: Y[row*256 + col0+col] += acc        (shape GEMM, N=256)
// EPI 2: Y[(cg>>8)*sstr + row*256 + (cg&255)] = acc   (G precompute, N=768)
struct MArgs {
    const unsigned short *Ahi, *Alo; int lda;
    const unsigned short *Bhi, *Blo; int K;  // Bt row-major [N][K]
    float* Y;
    int sstr;
    int V;
};

template <int EPI>
__global__ __launch_bounds__(256) void mgemm(MArgs g) {
    __shared__ unsigned short As_hi[64][40], As_lo[64][40];
    __shared__ unsigned short Bs_hi[128][40], Bs_lo[128][40];
    int tid = threadIdx.x;
    int row0 = blockIdx.y * 64;
    int col0 = blockIdx.x * 128;
    int l = tid & 63, wid = tid >> 6;
    int wr = wid & 1, wc = wid >> 1;
    int lw = l & 15, gg = l >> 4;
    f32x4v acc[2][4];
#pragma unroll
    for (int i = 0; i < 2; ++i)
#pragma unroll
        for (int j = 0; j < 4; ++j) acc[i][j] = (f32x4v){0.f, 0.f, 0.f, 0.f};

    int arow = tid >> 2, akoff = (tid & 3) * 8;
    for (int k0 = 0; k0 < g.K; k0 += 32) {
        __syncthreads();
        {
            int grow = row0 + arow;
            uint4 zh = make_uint4(0, 0, 0, 0), zl = make_uint4(0, 0, 0, 0);
            if (grow < g.V) {
                zh = *(const uint4*)(g.Ahi + (size_t)grow * g.lda + k0 + akoff);
                zl = *(const uint4*)(g.Alo + (size_t)grow * g.lda + k0 + akoff);
            }
            *(uint4*)&As_hi[arow][akoff] = zh;
            *(uint4*)&As_lo[arow][akoff] = zl;
        }
#pragma unroll
        for (int it = 0; it < 2; ++it) {
            int q = tid + it * 256;
            int n = q >> 2, koff = (q & 3) * 8;
            *(uint4*)&Bs_hi[n][koff] = *(const uint4*)(g.Bhi + (size_t)(col0 + n) * g.K + k0 + koff);
            *(uint4*)&Bs_lo[n][koff] = *(const uint4*)(g.Blo + (size_t)(col0 + n) * g.K + k0 + koff);
        }
        __syncthreads();
        bf16x8v ah[2], al[2], bh[4], bl[4];
#pragma unroll
        for (int mt = 0; mt < 2; ++mt) {
            int r = wr * 32 + mt * 16 + lw;
            ah[mt] = *(const bf16x8v*)&As_hi[r][gg * 8];
            al[mt] = *(const bf16x8v*)&As_lo[r][gg * 8];
        }
#pragma unroll
        for (int nt = 0; nt < 4; ++nt) {
            int c = wc * 64 + nt * 16 + lw;
            bh[nt] = *(const bf16x8v*)&Bs_hi[c][gg * 8];
            bl[nt] = *(const bf16x8v*)&Bs_lo[c][gg * 8];
        }
#pragma unroll
        for (int mt = 0; mt < 2; ++mt)
#pragma unroll
            for (int nt = 0; nt < 4; ++nt) {
                acc[mt][nt] = __builtin_amdgcn_mfma_f32_16x16x32_bf16(ah[mt], bh[nt], acc[mt][nt], 0, 0, 0);
                acc[mt][nt] = __builtin_amdgcn_mfma_f32_16x16x32_bf16(ah[mt], bl[nt], acc[mt][nt], 0, 0, 0);
                acc[mt][nt] = __builtin_amdgcn_mfma_f32_16x16x32_bf16(al[mt], bh[nt], acc[mt][nt], 0, 0, 0);
            }
    }
#pragma unroll
    for (int mt = 0; mt < 2; ++mt)
#pragma unroll
        for (int nt = 0; nt < 4; ++nt) {
            int colg = wc * 64 + nt * 16 + lw;
#pragma unroll
            for (int r = 0; r < 4; ++r) {
                int rowg = row0 + wr * 32 + mt * 16 + gg * 4 + r;
                if (rowg >= g.V) continue;
                float v = acc[mt][nt][r];
                if (EPI == 0) {
                    g.Y[(size_t)rowg * 256 + col0 + colg] += v;
                } else {
                    int cg = col0 + colg;
                    g.Y[(size_t)(cg >> 8) * g.sstr + (size_t)rowg * 256 + (cg & 255)] = v;
                }
            }
        }
}

// ---------------- input perceptual gather: Ybuf[v][0..255] ------------------
// G layout: [stage][pixel][256], pixel = map-local + {0, 3136, 3920}
__global__ void gather_kernel(const float* __restrict__ G, int sstr,
                              const int* __restrict__ sampi, const float* __restrict__ sampw,
                              float* __restrict__ Yb, int V, int stage,
                              const float* __restrict__ Win0, const float* __restrict__ Win1,
                              const float* __restrict__ shape) {
    int v = blockIdx.x;
    if (v >= V) return;
    int j = threadIdx.x;
    const float* Gs = G + (size_t)stage * sstr;
    int b = v * 12;
    float acc = 0.0f;
#pragma unroll
    for (int s = 0; s < 4; ++s)
        acc += sampw[b + s] * Gs[(size_t)sampi[b + s] * 256 + j];
#pragma unroll
    for (int s = 0; s < 4; ++s)
        acc += sampw[b + 4 + s] * Gs[(size_t)(3136 + sampi[b + 4 + s]) * 256 + j];
#pragma unroll
    for (int s = 0; s < 4; ++s)
        acc += sampw[b + 8 + s] * Gs[(size_t)(3920 + sampi[b + 8 + s]) * 256 + j];
    if (stage == 0) {
#pragma unroll
        for (int k = 0; k < 3; ++k) {
            float w = shape[v * 3 + k];
            float wv = (j < 128) ? Win0[(size_t)(1280 + k) * 128 + j]
                                 : Win1[(size_t)(1280 + k) * 128 + (j - 128)];
            acc += w * wv;
        }
    }
    Yb[(size_t)v * 256 + j] = acc;
}

// ---------------- input-layer combine: h = relu(Y0 + agg(Y1) + b) ----------
__global__ __launch_bounds__(256) void combine_in(
    const float* __restrict__ Y, const float* __restrict__ bias,
    const int* __restrict__ rowptr, const int* __restrict__ dst,
    float* __restrict__ hout, int V) {
    int v = blockIdx.x * 2 + (threadIdx.x >> 7);
    int d = threadIdx.x & 127;
    if (v >= V) return;
    float val = Y[(size_t)v * 256 + d] + bias[d];
    int e0 = rowptr[v], e1 = rowptr[v + 1];
    for (int e = e0; e < e1; ++e) val += Y[(size_t)dst[e] * 256 + 128 + d];
    val = fmaxf(val, 0.0f);
    hout[(size_t)v * 128 + d] = val;
}

// ---------------- fused resnet layer: gather-agg + GEMM + epilogue ----------
// Block: 64 rows, 256 threads (4 waves). A = [h | agg(h)] built in LDS in two
// halves (agg half first, own half second so As holds own-h at epilogue time).
// K=256 in 8 steps of 32; B streamed from L2. Epilogue: relu(acc+b)+h -> hnext.
struct LArgs {
    const float* h;                                   // [V][128] f32
    const unsigned short *Bhi, *Blo;                  // [128][256]
    const int *rowptr, *dst;
    const float* bias;
    float* hnext;
    int V;
};

__global__ __launch_bounds__(256) void lay_kernel(LArgs g) {
    __shared__ unsigned short As_hi[64][136], As_lo[64][136];
    __shared__ unsigned short Bs_hi[128][40], Bs_lo[128][40];
    int tid = threadIdx.x;
    int row0 = blockIdx.x * 64;
    int l = tid & 63, wid = tid >> 6;
    int wr = wid & 1, wc = wid >> 1;
    int lw = l & 15, gg = l >> 4;
    int arow = tid >> 2;
    int acq = (tid & 3) * 32;
    int grow = row0 + arow;

    f32x4v acc[2][4];
#pragma unroll
    for (int i = 0; i < 2; ++i)
#pragma unroll
        for (int j = 0; j < 4; ++j) acc[i][j] = (f32x4v){0.f, 0.f, 0.f, 0.f};

    float vals[32];

    auto store_half = [&]() {
        unsigned short hh[8], ll[8];
#pragma unroll
        for (int c = 0; c < 4; ++c) {
#pragma unroll
            for (int i = 0; i < 8; ++i) f2hl(vals[c * 8 + i], hh[i], ll[i]);
            *(uint4*)&As_hi[arow][acq + c * 8] = *(uint4*)hh;
            *(uint4*)&As_lo[arow][acq + c * 8] = *(uint4*)ll;
        }
    };

    auto mfma_step = [&](int ks, int kglob0) {
        // load B tile for k = kglob0..kglob0+32
#pragma unroll
        for (int it = 0; it < 2; ++it) {
            int q = tid + it * 256;
            int n = q >> 2, koff = (q & 3) * 8;
            *(uint4*)&Bs_hi[n][koff] = *(const uint4*)(g.Bhi + (size_t)n * 256 + kglob0 + koff);
            *(uint4*)&Bs_lo[n][koff] = *(const uint4*)(g.Blo + (size_t)n * 256 + kglob0 + koff);
        }
        __syncthreads();
        bf16x8v ah[2], al[2], bh[4], bl[4];
        int kk = ks * 32 + gg * 8;
#pragma unroll
        for (int mt = 0; mt < 2; ++mt) {
            int r = wr * 32 + mt * 16 + lw;
            ah[mt] = *(const bf16x8v*)&As_hi[r][kk];
            al[mt] = *(const bf16x8v*)&As_lo[r][kk];
        }
#pragma unroll
        for (int nt = 0; nt < 4; ++nt) {
            int c = wc * 64 + nt * 16 + lw;
            bh[nt] = *(const bf16x8v*)&Bs_hi[c][gg * 8];
            bl[nt] = *(const bf16x8v*)&Bs_lo[c][gg * 8];
        }
#pragma unroll
        for (int mt = 0; mt < 2; ++mt)
#pragma unroll
            for (int nt = 0; nt < 4; ++nt) {
                acc[mt][nt] = __builtin_amdgcn_mfma_f32_16x16x32_bf16(ah[mt], bh[nt], acc[mt][nt], 0, 0, 0);
                acc[mt][nt] = __builtin_amdgcn_mfma_f32_16x16x32_bf16(ah[mt], bl[nt], acc[mt][nt], 0, 0, 0);
                acc[mt][nt] = __builtin_amdgcn_mfma_f32_16x16x32_bf16(al[mt], bh[nt], acc[mt][nt], 0, 0, 0);
            }
        __syncthreads();
    };

    // ---- phase 1: agg half (k-global 128..255) ----
#pragma unroll
    for (int i = 0; i < 32; ++i) vals[i] = 0.0f;
    if (grow < g.V) {
        int e0 = g.rowptr[grow], e1 = g.rowptr[grow + 1];
        for (int e = e0; e < e1; ++e) {
            const float* hp = g.h + (size_t)g.dst[e] * 128 + acq;
#pragma unroll
            for (int c = 0; c < 8; ++c) {
                float4 f = *(const float4*)(hp + c * 4);
                vals[c * 4 + 0] += f.x;
                vals[c * 4 + 1] += f.y;
                vals[c * 4 + 2] += f.z;
                vals[c * 4 + 3] += f.w;
            }
        }
    }
    store_half();
    for (int ks = 0; ks < 4; ++ks) mfma_step(ks, 128 + ks * 32);

    // ---- phase 2: own half (k-global 0..127) ----
    if (grow < g.V) {
        const float* hp = g.h + (size_t)grow * 128 + acq;
#pragma unroll
        for (int c = 0; c < 8; ++c) {
            float4 f = *(const float4*)(hp + c * 4);
            vals[c * 4 + 0] = f.x;
            vals[c * 4 + 1] = f.y;
            vals[c * 4 + 2] = f.z;
            vals[c * 4 + 3] = f.w;
        }
    } else {
#pragma unroll
        for (int i = 0; i < 32; ++i) vals[i] = 0.0f;
    }
    store_half();
    for (int ks = 0; ks < 4; ++ks) mfma_step(ks, ks * 32);

    // ---- epilogue: hnext = relu(acc + bias) + h ----
#pragma unroll
    for (int mt = 0; mt < 2; ++mt)
#pragma unroll
        for (int nt = 0; nt < 4; ++nt) {
            int colg = wc * 64 + nt * 16 + lw;
            float bv = g.bias[colg];
#pragma unroll
            for (int r = 0; r < 4; ++r) {
                int rowg = row0 + wr * 32 + mt * 16 + gg * 4 + r;
                if (rowg >= g.V) continue;
                float v = acc[mt][nt][r] + bv;
                v = fmaxf(v, 0.0f);
                v += g.h[(size_t)rowg * 128 + colg];
                g.hnext[(size_t)rowg * 128 + colg] = v;
            }
        }
}

// ---------------- coord head ------------------------------------------------
__global__ void coordgemm_kernel(const float* __restrict__ h,
                                 const float* __restrict__ Wc0, const float* __restrict__ Wc1,
                                 int V, float* __restrict__ Yc) {
    int idx = blockIdx.x * 256 + threadIdx.x;
    if (idx >= V * 6) return;
    int v = idx / 6, j = idx % 6;
    const float* W = (j < 3) ? Wc0 : Wc1;
    int jj = (j < 3) ? j : j - 3;
    const float* hp = h + (size_t)v * 128;
    float acc = 0.0f;
#pragma unroll 8
    for (int k = 0; k < 128; ++k) acc += hp[k] * W[k * 3 + jj];
    Yc[idx] = acc;
}

__global__ void coordcombine_kernel(const float* __restrict__ Yc, const float* __restrict__ bc,
                                    const int* __restrict__ rowptr, const int* __restrict__ dst,
                                    int V, float* __restrict__ out) {
    int idx = blockIdx.x * 256 + threadIdx.x;
    if (idx >= V * 3) return;
    int v = idx / 3, j = idx % 3;
    float val = Yc[(size_t)v * 6 + j] + bc[j];
    int e0 = rowptr[v], e1 = rowptr[v + 1];
    for (int e = e0; e < e1; ++e) val += Yc[(size_t)dst[e] * 6 + 3 + j];
    out[(size_t)v * 3 + j] = val;
}

// ---------------- unpool: verts midpoints + featpack hi/lo ------------------
__global__ void unpool_kernel(float* __restrict__ verts, const float* __restrict__ h,
                              const int* __restrict__ mid, int V, int Nm,
                              unsigned short* __restrict__ fphi, unsigned short* __restrict__ fplo) {
    int r = blockIdx.x;
    int t = threadIdx.x;  // 128
    if (r < V) {
        float v = h[(size_t)r * 128 + t];
        unsigned short hi, lo;
        f2hl(v, hi, lo);
        fphi[(size_t)r * 128 + t] = hi;
        fplo[(size_t)r * 128 + t] = lo;
    } else {
        int i = r - V;
        int a = mid[2 * i], b = mid[2 * i + 1];
        float v = 0.5f * (h[(size_t)a * 128 + t] + h[(size_t)b * 128 + t]);
        unsigned short hi, lo;
        f2hl(v, hi, lo);
        fphi[(size_t)r * 128 + t] = hi;
        fplo[(size_t)r * 128 + t] = lo;
        if (t < 3)
            verts[(size_t)r * 3 + t] = 0.5f * (verts[(size_t)a * 3 + t] + verts[(size_t)b * 3 + t]);
    }
}

// ---------------------------------------------------------------------------
extern "C" void kernel_launch(void* const* d_in, const int* in_sizes, int n_in,
                              void* d_out, int out_size, void* d_ws, size_t ws_size,
                              hipStream_t stream) {
    const float* f3 = (const float*)d_in[0];
    const float* f4 = (const float*)d_in[1];
    const float* f5 = (const float*)d_in[2];
    const float* verts0 = (const float*)d_in[3];
    const float* cam_c = (const float*)d_in[4];
    const float* cam_f = (const float*)d_in[5];
    const int* imgsz = (const int*)d_in[38];

    int V0 = in_sizes[3] / 3;
    int E[3] = {in_sizes[33] / 2, in_sizes[34] / 2, in_sizes[35] / 2};
    int Nm0 = in_sizes[36] / 2, Nm1 = in_sizes[37] / 2;
    int V1 = V0 + Nm0, V2 = V1 + Nm1;
    int Vs[3] = {V0, V1, V2};
    const int NPIXT = 3136 + 784 + 196;  // 4116
    const int GS = NPIXT * 256;          // per-stage G stride (floats)

    // ---- workspace (byte allocator, 256B aligned) ----
    char* wsp = (char*)d_ws;
    auto alloc = [&](size_t bytes) -> void* {
        void* p = (void*)wsp;
        wsp += (bytes + 255) & ~(size_t)255;
        return p;
    };
    unsigned short* ft0h = (unsigned short*)alloc((size_t)3136 * 256 * 2);
    unsigned short* ft0l = (unsigned short*)alloc((size_t)3136 * 256 * 2);
    unsigned short* ft1h = (unsigned short*)alloc((size_t)784 * 512 * 2);
    unsigned short* ft1l = (unsigned short*)alloc((size_t)784 * 512 * 2);
    unsigned short* ft2h = (unsigned short*)alloc((size_t)196 * 512 * 2);
    unsigned short* ft2l = (unsigned short*)alloc((size_t)196 * 512 * 2);
    unsigned short* Bg0h = (unsigned short*)alloc((size_t)768 * 256 * 2);
    unsigned short* Bg0l = (unsigned short*)alloc((size_t)768 * 256 * 2);
    unsigned short* Bg1h = (unsigned short*)alloc((size_t)768 * 512 * 2);
    unsigned short* Bg1l = (unsigned short*)alloc((size_t)768 * 512 * 2);
    unsigned short* Bg2h = (unsigned short*)alloc((size_t)768 * 512 * 2);
    unsigned short* Bg2l = (unsigned short*)alloc((size_t)768 * 512 * 2);
    float* Gbuf = (float*)alloc((size_t)3 * GS * 4);
    unsigned short* BtLhi = (unsigned short*)alloc((size_t)12 * 128 * 256 * 2);
    unsigned short* BtLlo = (unsigned short*)alloc((size_t)12 * 128 * 256 * 2);
    unsigned short* BtShi = (unsigned short*)alloc((size_t)256 * 128 * 2);
    unsigned short* BtSlo = (unsigned short*)alloc((size_t)256 * 128 * 2);
    float* Ybuf = (float*)alloc((size_t)V2 * 256 * 4);
    float* hA = (float*)alloc((size_t)V2 * 128 * 4);
    float* hB = (float*)alloc((size_t)V2 * 128 * 4);
    unsigned short* FPhi = (unsigned short*)alloc((size_t)V2 * 128 * 2);
    unsigned short* FPlo = (unsigned short*)alloc((size_t)V2 * 128 * 2);
    float* vertsbuf = (float*)alloc((size_t)V2 * 3 * 4);
    float* Yc = (float*)alloc((size_t)V2 * 6 * 4);
    int* sampi = (int*)alloc((size_t)V2 * 12 * 4);
    float* sampw = (float*)alloc((size_t)V2 * 12 * 4);
    int* rowptr = (int*)alloc(((size_t)V2 + 1) * 4);

    // ---- feature map transpose + hi/lo split ----
    transpose_hl<<<DIV_UP(256 * 56 * 56, 256), 256, 0, stream>>>(f3, ft0h, ft0l, 256, 56 * 56);
    transpose_hl<<<DIV_UP(512 * 28 * 28, 256), 256, 0, stream>>>(f4, ft1h, ft1l, 512, 28 * 28);
    transpose_hl<<<DIV_UP(512 * 14 * 14, 256), 256, 0, stream>>>(f5, ft2h, ft2l, 512, 14 * 14);

    const float* W0s_[3] = {(const float*)d_in[6], (const float*)d_in[15], (const float*)d_in[24]};
    const float* W1s_[3] = {(const float*)d_in[7], (const float*)d_in[16], (const float*)d_in[25]};

    // ---- G precompute (MFMA): G[s][pix][256] = ft_m @ W-slice ----
    pack_gb_bt<<<DIV_UP(768 * 256, 256), 256, 0, stream>>>(W0s_[0], W1s_[0], W0s_[1], W1s_[1],
                                                           W0s_[2], W1s_[2], Bg0h, Bg0l, 0, 256);
    pack_gb_bt<<<DIV_UP(768 * 512, 256), 256, 0, stream>>>(W0s_[0], W1s_[0], W0s_[1], W1s_[1],
                                                           W0s_[2], W1s_[2], Bg1h, Bg1l, 256, 512);
    pack_gb_bt<<<DIV_UP(768 * 512, 256), 256, 0, stream>>>(W0s_[0], W1s_[0], W0s_[1], W1s_[1],
                                                           W0s_[2], W1s_[2], Bg2h, Bg2l, 768, 512);
    {
        MArgs m = {};
        m.sstr = GS;
        // map 0 (3136 px, K=256) -> G rows [0,3136)
        m.Ahi = ft0h; m.Alo = ft0l; m.lda = 256;
        m.Bhi = Bg0h; m.Blo = Bg0l; m.K = 256;
        m.Y = Gbuf; m.V = 3136;
        dim3 g0(6, DIV_UP(3136, 64));
        mgemm<2><<<g0, 256, 0, stream>>>(m);
        // map 1 (784 px, K=512) -> G rows [3136,3920)
        m.Ahi = ft1h; m.Alo = ft1l; m.lda = 512;
        m.Bhi = Bg1h; m.Blo = Bg1l; m.K = 512;
        m.Y = Gbuf + (size_t)3136 * 256; m.V = 784;
        dim3 g1(6, DIV_UP(784, 64));
        mgemm<2><<<g1, 256, 0, stream>>>(m);
        // map 2 (196 px, K=512) -> G rows [3920,4116)
        m.Ahi = ft2h; m.Alo = ft2l; m.lda = 512;
        m.Bhi = Bg2h; m.Blo = Bg2l; m.K = 512;
        m.Y = Gbuf + (size_t)3920 * 256; m.V = 196;
        dim3 g2(6, DIV_UP(196, 64));
        mgemm<2><<<g2, 256, 0, stream>>>(m);
    }

    for (int si = 0; si < 3; ++si) {
        const float* Win0 = (const float*)d_in[6 + si * 9 + 0];
        const float* Win1 = (const float*)d_in[6 + si * 9 + 1];
        const float* bin = (const float*)d_in[6 + si * 9 + 2];
        const float* W0L = (const float*)d_in[6 + si * 9 + 3];
        const float* W1L = (const float*)d_in[6 + si * 9 + 4];
        const float* bs = (const float*)d_in[6 + si * 9 + 5];
        const float* Wc0 = (const float*)d_in[6 + si * 9 + 6];
        const float* Wc1 = (const float*)d_in[6 + si * 9 + 7];
        const float* bc = (const float*)d_in[6 + si * 9 + 8];
        const int* edges = (const int*)d_in[33 + si];
        int Ecur = E[si];
        const int* esrc = edges;
        const int* edst = edges + Ecur;
        int V = Vs[si];
        const float* vertsin = (si == 0) ? verts0 : vertsbuf;

        pack_lay_bt<<<12 * 128, 256, 0, stream>>>(W0L, W1L, BtLhi, BtLlo);
        if (si > 0) pack_sh_bt<<<128, 256, 0, stream>>>(Win0, Win1, BtShi, BtSlo);
        desc_kernel<<<DIV_UP(V, 256), 256, 0, stream>>>(vertsin, cam_c, cam_f, imgsz, V,
                                                        sampi, sampw);
        rowptr_kernel<<<DIV_UP(V + 1, 256), 256, 0, stream>>>(esrc, Ecur, V, rowptr);

        // input gconv: perceptual gather (+stage0 shape), then shape GEMM (si>0)
        gather_kernel<<<V, 256, 0, stream>>>(Gbuf, GS, sampi, sampw, Ybuf, V, si, Win0, Win1,
                                             (si == 0) ? verts0 : nullptr);
        if (si > 0) {
            MArgs m = {};
            m.Ahi = FPhi; m.Alo = FPlo; m.lda = 128;
            m.Bhi = BtShi; m.Blo = BtSlo; m.K = 128;
            m.Y = Ybuf; m.V = V;
            dim3 grid(2, DIV_UP(V, 64));
            mgemm<0><<<grid, 256, 0, stream>>>(m);
        }
        combine_in<<<DIV_UP(V, 2), 256, 0, stream>>>(Ybuf, bin, rowptr, edst, hA, V);

        float* hcur = hA;
        float* hnext = hB;
        for (int ll = 0; ll < 12; ++ll) {
            LArgs a = {};
            a.h = hcur;
            a.Bhi = BtLhi + (size_t)ll * 32768;
            a.Blo = BtLlo + (size_t)ll * 32768;
            a.rowptr = rowptr; a.dst = edst;
            a.bias = bs + (size_t)ll * 128;
            a.hnext = hnext;
            a.V = V;
            lay_kernel<<<DIV_UP(V, 64), 256, 0, stream>>>(a);
            float* t = hcur; hcur = hnext; hnext = t;
        }

        coordgemm_kernel<<<DIV_UP(V * 6, 256), 256, 0, stream>>>(hcur, Wc0, Wc1, V, Yc);
        float* ctarget = (si == 2) ? (float*)d_out : vertsbuf;
        coordcombine_kernel<<<DIV_UP(V * 3, 256), 256, 0, stream>>>(Yc, bc, rowptr, edst, V,
                                                                    ctarget);
        if (si < 2) {
            const int* mid = (const int*)d_in[36 + si];
            int Nm = (si == 0) ? Nm0 : Nm1;
            unpool_kernel<<<V + Nm, 128, 0, stream>>>(vertsbuf, hcur, mid, V, Nm, FPhi, FPlo);
        }
    }
}

// Round 4
// 1511.457 us; speedup vs baseline: 2.1629x; 1.0119x over previous
//
#include <hip/hip_runtime.h>
#include <hip/hip_bf16.h>
#include <cstddef>
#include <cstdint>

#define DIV_UP(a, b) (((a) + (b) - 1) / (b))

typedef __attribute__((ext_vector_type(8))) short bf16x8v;
typedef __attribute__((ext_vector_type(4))) float f32x4v;

__device__ __forceinline__ unsigned short bf16_rn(float v) {
    unsigned int u = __float_as_uint(v);
    unsigned int r = (u + 0x7FFFu + ((u >> 16) & 1u)) >> 16;
    return (unsigned short)r;
}
__device__ __forceinline__ float bf16_f(unsigned short h) {
    return __uint_as_float(((unsigned int)h) << 16);
}
__device__ __forceinline__ void f2hl(float v, unsigned short& hi, unsigned short& lo) {
    hi = bf16_rn(v);
    float r = v - bf16_f(hi);
    lo = bf16_rn(r);
}

// ---------------- transpose (C,H,W) f32 -> (H*W, C) bf16 hi/lo --------------
__global__ void transpose_hl(const float* __restrict__ in, unsigned short* __restrict__ ohi,
                             unsigned short* __restrict__ olo, int C, int HW) {
    int idx = blockIdx.x * 256 + threadIdx.x;
    if (idx >= C * HW) return;
    int c = idx % C;
    int p = idx / C;
    float v = in[(size_t)c * HW + p];
    unsigned short hi, lo;
    f2hl(v, hi, lo);
    ohi[(size_t)p * C + c] = hi;
    olo[(size_t)p * C + c] = lo;
}

// ------------- pack G-weights transposed: Bt[n=768][k=C] hi/lo --------------
__global__ void pack_gb_bt(const float* __restrict__ W00, const float* __restrict__ W01,
                           const float* __restrict__ W10, const float* __restrict__ W11,
                           const float* __restrict__ W20, const float* __restrict__ W21,
                           unsigned short* __restrict__ Bhi, unsigned short* __restrict__ Blo,
                           int base, int C) {
    int idx = blockIdx.x * 256 + threadIdx.x;
    if (idx >= 768 * C) return;
    int n = idx / C, k = idx % C;
    int s = n >> 8, j = n & 255;
    const float* W0 = (s == 0) ? W00 : (s == 1) ? W10 : W20;
    const float* W1 = (s == 0) ? W01 : (s == 1) ? W11 : W21;
    float v = (j < 128) ? W0[(size_t)(base + k) * 128 + j]
                        : W1[(size_t)(base + k) * 128 + (j - 128)];
    unsigned short hi, lo;
    f2hl(v, hi, lo);
    Bhi[idx] = hi;
    Blo[idx] = lo;
}

// ------------- pack layer weights, transposed, bf16 hi/lo -------------------
__global__ void pack_lay_bt(const float* __restrict__ W0, const float* __restrict__ W1,
                            unsigned short* __restrict__ Bhi, unsigned short* __restrict__ Blo) {
    int idx = blockIdx.x * 256 + threadIdx.x;  // 12*128*256
    int l = idx >> 15;
    int r = idx & 32767;
    int n = r >> 8, k = r & 255;
    float v = (k < 128) ? W0[(size_t)l * 16384 + k * 128 + n]
                        : W1[(size_t)l * 16384 + (k - 128) * 128 + n];
    unsigned short hi, lo;
    f2hl(v, hi, lo);
    Bhi[idx] = hi;
    Blo[idx] = lo;
}

// ------------- pack shape-input weights (rows 1280..1407), transposed -------
__global__ void pack_sh_bt(const float* __restrict__ Win0, const float* __restrict__ Win1,
                           unsigned short* __restrict__ Bhi, unsigned short* __restrict__ Blo) {
    int idx = blockIdx.x * 256 + threadIdx.x;  // 256*128
    if (idx >= 256 * 128) return;
    int n = idx >> 7, k = idx & 127;
    float v = (n < 128) ? Win0[(size_t)(1280 + k) * 128 + n]
                        : Win1[(size_t)(1280 + k) * 128 + (n - 128)];
    unsigned short hi, lo;
    f2hl(v, hi, lo);
    Bhi[idx] = hi;
    Blo[idx] = lo;
}

// ---------------- per-vertex projection + bilerp descriptors ----------------
__global__ void desc_kernel(const float* __restrict__ verts,
                            const float* __restrict__ cam_c, const float* __restrict__ cam_f,
                            const int* __restrict__ imgsz, int V,
                            int* __restrict__ sampi, float* __restrict__ sampw) {
    int v = blockIdx.x * 256 + threadIdx.x;
    if (v >= V) return;
    float X = verts[3 * v + 0], Yy = verts[3 * v + 1], Z = verts[3 * v + 2];
    float cx = cam_c[0], cy = cam_c[1], fx = cam_f[0], fy = cam_f[1];
    const float tz = 0.8f;
    float pz = Z + tz;
    float px = (fx * X + cx * Z + tz * cx) / pz;
    float py = (fy * Yy + cy * Z + tz * cy) / pz;
    float is = (float)imgsz[0];
    const int Ss[3] = {56, 28, 14};
#pragma unroll
    for (int m = 0; m < 3; ++m) {
        int S = Ss[m];
        float dim = (float)S;
        float x = px * dim / is;
        float y = py * dim / is;
        float x1 = floorf(x), y1 = floorf(y);
        float x2 = x1 + 1.0f, y2 = y1 + 1.0f;
        float smax = (float)(S - 1);
        int xi1 = (int)fminf(fmaxf(x1, 0.0f), smax);
        int xi2 = (int)fminf(fmaxf(x2, 0.0f), smax);
        int yi1 = (int)fminf(fmaxf(y1, 0.0f), smax);
        int yi2 = (int)fminf(fmaxf(y2, 0.0f), smax);
        int b = v * 12 + m * 4;
        sampi[b + 0] = xi1 * S + yi1;
        sampi[b + 1] = xi1 * S + yi2;
        sampi[b + 2] = xi2 * S + yi1;
        sampi[b + 3] = xi2 * S + yi2;
        sampw[b + 0] = (x2 - x) * (y2 - y);
        sampw[b + 1] = (x2 - x) * (y - y1);
        sampw[b + 2] = (x - x1) * (y2 - y);
        sampw[b + 3] = (x - x1) * (y - y1);
    }
}

// ---------------- rowptr from sorted src array ------------------------------
__global__ void rowptr_kernel(const int* __restrict__ src, int E, int V, int* __restrict__ rowptr) {
    int v = blockIdx.x * 256 + threadIdx.x;
    if (v > V) return;
    int lo = 0, hi = E;
    while (lo < hi) {
        int mid = (lo + hi) >> 1;
        if (src[mid] < v) lo = mid + 1; else hi = mid;
    }
    rowptr[v] = lo;
}

// ---------------- MFMA bf16x3 GEMM (shape GEMM + G precompute) --------------
struct MArgs {
    const unsigned short *Ahi, *Alo; int lda;
    const unsigned short *Bhi, *Blo; int K;  // Bt row-major [N][K]
    float* Y;
    int sstr;
    int V;
};

template <int EPI>
__global__ __launch_bounds__(256) void mgemm(MArgs g) {
    __shared__ unsigned short As_hi[64][40], As_lo[64][40];
    __shared__ unsigned short Bs_hi[128][40], Bs_lo[128][40];
    int tid = threadIdx.x;
    int row0 = blockIdx.y * 64;
    int col0 = blockIdx.x * 128;
    int l = tid & 63, wid = tid >> 6;
    int wr = wid & 1, wc = wid >> 1;
    int lw = l & 15, gg = l >> 4;
    f32x4v acc[2][4];
#pragma unroll
    for (int i = 0; i < 2; ++i)
#pragma unroll
        for (int j = 0; j < 4; ++j) acc[i][j] = (f32x4v){0.f, 0.f, 0.f, 0.f};

    int arow = tid >> 2, akoff = (tid & 3) * 8;
    for (int k0 = 0; k0 < g.K; k0 += 32) {
        __syncthreads();
        {
            int grow = row0 + arow;
            uint4 zh = make_uint4(0, 0, 0, 0), zl = make_uint4(0, 0, 0, 0);
            if (grow < g.V) {
                zh = *(const uint4*)(g.Ahi + (size_t)grow * g.lda + k0 + akoff);
                zl = *(const uint4*)(g.Alo + (size_t)grow * g.lda + k0 + akoff);
            }
            *(uint4*)&As_hi[arow][akoff] = zh;
            *(uint4*)&As_lo[arow][akoff] = zl;
        }
#pragma unroll
        for (int it = 0; it < 2; ++it) {
            int q = tid + it * 256;
            int n = q >> 2, koff = (q & 3) * 8;
            *(uint4*)&Bs_hi[n][koff] = *(const uint4*)(g.Bhi + (size_t)(col0 + n) * g.K + k0 + koff);
            *(uint4*)&Bs_lo[n][koff] = *(const uint4*)(g.Blo + (size_t)(col0 + n) * g.K + k0 + koff);
        }
        __syncthreads();
        bf16x8v ah[2], al[2], bh[4], bl[4];
#pragma unroll
        for (int mt = 0; mt < 2; ++mt) {
            int r = wr * 32 + mt * 16 + lw;
            ah[mt] = *(const bf16x8v*)&As_hi[r][gg * 8];
            al[mt] = *(const bf16x8v*)&As_lo[r][gg * 8];
        }
#pragma unroll
        for (int nt = 0; nt < 4; ++nt) {
            int c = wc * 64 + nt * 16 + lw;
            bh[nt] = *(const bf16x8v*)&Bs_hi[c][gg * 8];
            bl[nt] = *(const bf16x8v*)&Bs_lo[c][gg * 8];
        }
#pragma unroll
        for (int mt = 0; mt < 2; ++mt)
#pragma unroll
            for (int nt = 0; nt < 4; ++nt) {
                acc[mt][nt] = __builtin_amdgcn_mfma_f32_16x16x32_bf16(ah[mt], bh[nt], acc[mt][nt], 0, 0, 0);
                acc[mt][nt] = __builtin_amdgcn_mfma_f32_16x16x32_bf16(ah[mt], bl[nt], acc[mt][nt], 0, 0, 0);
                acc[mt][nt] = __builtin_amdgcn_mfma_f32_16x16x32_bf16(al[mt], bh[nt], acc[mt][nt], 0, 0, 0);
            }
    }
#pragma unroll
    for (int mt = 0; mt < 2; ++mt)
#pragma unroll
        for (int nt = 0; nt < 4; ++nt) {
            int colg = wc * 64 + nt * 16 + lw;
#pragma unroll
            for (int r = 0; r < 4; ++r) {
                int rowg = row0 + wr * 32 + mt * 16 + gg * 4 + r;
                if (rowg >= g.V) continue;
                float v = acc[mt][nt][r];
                if (EPI == 0) {
                    g.Y[(size_t)rowg * 256 + col0 + colg] += v;
                } else {
                    int cg = col0 + colg;
                    g.Y[(size_t)(cg >> 8) * g.sstr + (size_t)rowg * 256 + (cg & 255)] = v;
                }
            }
        }
}

// ---------------- input perceptual gather: Ybuf[v][0..255] ------------------
__global__ void gather_kernel(const float* __restrict__ G, int sstr,
                              const int* __restrict__ sampi, const float* __restrict__ sampw,
                              float* __restrict__ Yb, int V, int stage,
                              const float* __restrict__ Win0, const float* __restrict__ Win1,
                              const float* __restrict__ shape) {
    int v = blockIdx.x;
    if (v >= V) return;
    int j = threadIdx.x;
    const float* Gs = G + (size_t)stage * sstr;
    int b = v * 12;
    float acc = 0.0f;
#pragma unroll
    for (int s = 0; s < 4; ++s)
        acc += sampw[b + s] * Gs[(size_t)sampi[b + s] * 256 + j];
#pragma unroll
    for (int s = 0; s < 4; ++s)
        acc += sampw[b + 4 + s] * Gs[(size_t)(3136 + sampi[b + 4 + s]) * 256 + j];
#pragma unroll
    for (int s = 0; s < 4; ++s)
        acc += sampw[b + 8 + s] * Gs[(size_t)(3920 + sampi[b + 8 + s]) * 256 + j];
    if (stage == 0) {
#pragma unroll
        for (int k = 0; k < 3; ++k) {
            float w = shape[v * 3 + k];
            float wv = (j < 128) ? Win0[(size_t)(1280 + k) * 128 + j]
                                 : Win1[(size_t)(1280 + k) * 128 + (j - 128)];
            acc += w * wv;
        }
    }
    Yb[(size_t)v * 256 + j] = acc;
}

// ---------------- input-layer combine: h = relu(Y0 + agg(Y1) + b) ----------
__global__ __launch_bounds__(256) void combine_in(
    const float* __restrict__ Y, const float* __restrict__ bias,
    const int* __restrict__ rowptr, const int* __restrict__ dst,
    float* __restrict__ hout, int V) {
    int v = blockIdx.x * 2 + (threadIdx.x >> 7);
    int d = threadIdx.x & 127;
    if (v >= V) return;
    float val = Y[(size_t)v * 256 + d] + bias[d];
    int e0 = rowptr[v], e1 = rowptr[v + 1];
    for (int e = e0; e < e1; ++e) val += Y[(size_t)dst[e] * 256 + 128 + d];
    val = fmaxf(val, 0.0f);
    hout[(size_t)v * 128 + d] = val;
}

// ---------------- fused resnet layer: gather-agg + GEMM + epilogue ----------
// Block: 64 rows, 256 threads (4 waves). A=[h|agg(h)], K=256 in 8 steps of 32.
// As is staged PER K-STEP (only the 32-wide slice owned by threads tid&3==ks),
// LDS = 30.7 KB -> 5 blocks/CU. Own-half steps first (h in regs), then CSR
// agg, then agg-half steps. XCD-bijective block swizzle for L2 locality.
struct LArgs {
    const float* h;                                   // [V][128] f32
    const unsigned short *Bhi, *Blo;                  // [128][256]
    const int *rowptr, *dst;
    const float* bias;
    float* hnext;
    int V;
};

__global__ __launch_bounds__(256) void lay_kernel(LArgs g) {
    __shared__ unsigned short As_hi[64][40], As_lo[64][40];
    __shared__ unsigned short Bs_hi[128][40], Bs_lo[128][40];
    int tid = threadIdx.x;

    // bijective XCD swizzle (m204): contiguous block chunks per XCD
    int nwg = gridDim.x;
    int orig = blockIdx.x;
    int qq = nwg >> 3, rr = nwg & 7;
    int xcd = orig & 7, idx = orig >> 3;
    int bid = (xcd < rr ? xcd * (qq + 1) : rr * (qq + 1) + (xcd - rr) * qq) + idx;
    int row0 = bid * 64;

    int l = tid & 63, wid = tid >> 6;
    int wr = wid & 1, wc = wid >> 1;
    int lw = l & 15, gg = l >> 4;
    int arow = tid >> 2;
    int aq = tid & 3;           // k-slice owner: cols aq*32..aq*32+31
    int grow = row0 + arow;

    f32x4v acc[2][4];
#pragma unroll
    for (int i = 0; i < 2; ++i)
#pragma unroll
        for (int j = 0; j < 4; ++j) acc[i][j] = (f32x4v){0.f, 0.f, 0.f, 0.f};

    float vals[32];

    auto mfma_step = [&](int ks, int kglob0) {
        // issue B global loads first (VMEM), then As conversion (VALU)
        uint4 b0h, b1h, b0l, b1l;
        {
            int n0 = tid >> 2, koff = (tid & 3) * 8;
            b0h = *(const uint4*)(g.Bhi + (size_t)n0 * 256 + kglob0 + koff);
            b0l = *(const uint4*)(g.Blo + (size_t)n0 * 256 + kglob0 + koff);
            int n1 = n0 + 64;
            b1h = *(const uint4*)(g.Bhi + (size_t)n1 * 256 + kglob0 + koff);
            b1l = *(const uint4*)(g.Blo + (size_t)n1 * 256 + kglob0 + koff);
        }
        if (aq == ks) {
            unsigned short hh[8], ll[8];
#pragma unroll
            for (int c = 0; c < 4; ++c) {
#pragma unroll
                for (int i = 0; i < 8; ++i) f2hl(vals[c * 8 + i], hh[i], ll[i]);
                *(uint4*)&As_hi[arow][c * 8] = *(uint4*)hh;
                *(uint4*)&As_lo[arow][c * 8] = *(uint4*)ll;
            }
        }
        {
            int n0 = tid >> 2, koff = (tid & 3) * 8;
            *(uint4*)&Bs_hi[n0][koff] = b0h;
            *(uint4*)&Bs_lo[n0][koff] = b0l;
            *(uint4*)&Bs_hi[n0 + 64][koff] = b1h;
            *(uint4*)&Bs_lo[n0 + 64][koff] = b1l;
        }
        __syncthreads();
        bf16x8v ah[2], al[2], bh[4], bl[4];
#pragma unroll
        for (int mt = 0; mt < 2; ++mt) {
            int r = wr * 32 + mt * 16 + lw;
            ah[mt] = *(const bf16x8v*)&As_hi[r][gg * 8];
            al[mt] = *(const bf16x8v*)&As_lo[r][gg * 8];
        }
#pragma unroll
        for (int nt = 0; nt < 4; ++nt) {
            int c = wc * 64 + nt * 16 + lw;
            bh[nt] = *(const bf16x8v*)&Bs_hi[c][gg * 8];
            bl[nt] = *(const bf16x8v*)&Bs_lo[c][gg * 8];
        }
#pragma unroll
        for (int mt = 0; mt < 2; ++mt)
#pragma unroll
            for (int nt = 0; nt < 4; ++nt) {
                acc[mt][nt] = __builtin_amdgcn_mfma_f32_16x16x32_bf16(ah[mt], bh[nt], acc[mt][nt], 0, 0, 0);
                acc[mt][nt] = __builtin_amdgcn_mfma_f32_16x16x32_bf16(ah[mt], bl[nt], acc[mt][nt], 0, 0, 0);
                acc[mt][nt] = __builtin_amdgcn_mfma_f32_16x16x32_bf16(al[mt], bh[nt], acc[mt][nt], 0, 0, 0);
            }
        __syncthreads();
    };

    // ---- own half (k-global 0..127): h row slice in regs ----
    if (grow < g.V) {
        const float* hp = g.h + (size_t)grow * 128 + aq * 32;
#pragma unroll
        for (int c = 0; c < 8; ++c) {
            float4 f = *(const float4*)(hp + c * 4);
            vals[c * 4 + 0] = f.x;
            vals[c * 4 + 1] = f.y;
            vals[c * 4 + 2] = f.z;
            vals[c * 4 + 3] = f.w;
        }
    } else {
#pragma unroll
        for (int i = 0; i < 32; ++i) vals[i] = 0.0f;
    }
    for (int ks = 0; ks < 4; ++ks) mfma_step(ks, ks * 32);

    // ---- CSR aggregation into vals (k-global 128..255) ----
#pragma unroll
    for (int i = 0; i < 32; ++i) vals[i] = 0.0f;
    if (grow < g.V) {
        int e0 = g.rowptr[grow], e1 = g.rowptr[grow + 1];
        for (int e = e0; e < e1; ++e) {
            const float* hp = g.h + (size_t)g.dst[e] * 128 + aq * 32;
#pragma unroll
            for (int c = 0; c < 8; ++c) {
                float4 f = *(const float4*)(hp + c * 4);
                vals[c * 4 + 0] += f.x;
                vals[c * 4 + 1] += f.y;
                vals[c * 4 + 2] += f.z;
                vals[c * 4 + 3] += f.w;
            }
        }
    }
    for (int ks = 0; ks < 4; ++ks) mfma_step(ks, 128 + ks * 32);

    // ---- epilogue: hnext = relu(acc + bias) + h ----
#pragma unroll
    for (int mt = 0; mt < 2; ++mt)
#pragma unroll
        for (int nt = 0; nt < 4; ++nt) {
            int colg = wc * 64 + nt * 16 + lw;
            float bv = g.bias[colg];
#pragma unroll
            for (int r = 0; r < 4; ++r) {
                int rowg = row0 + wr * 32 + mt * 16 + gg * 4 + r;
                if (rowg >= g.V) continue;
                float v = acc[mt][nt][r] + bv;
                v = fmaxf(v, 0.0f);
                v += g.h[(size_t)rowg * 128 + colg];
                g.hnext[(size_t)rowg * 128 + colg] = v;
            }
        }
}

// ---------------- coord head ------------------------------------------------
__global__ void coordgemm_kernel(const float* __restrict__ h,
                                 const float* __restrict__ Wc0, const float* __restrict__ Wc1,
                                 int V, float* __restrict__ Yc) {
    int idx = blockIdx.x * 256 + threadIdx.x;
    if (idx >= V * 6) return;
    int v = idx / 6, j = idx % 6;
    const float* W = (j < 3) ? Wc0 : Wc1;
    int jj = (j < 3) ? j : j - 3;
    const float* hp = h + (size_t)v * 128;
    float acc = 0.0f;
#pragma unroll
    for (int k = 0; k < 32; ++k) {
        float4 f = *(const float4*)(hp + k * 4);
        acc += f.x * W[(k * 4 + 0) * 3 + jj];
        acc += f.y * W[(k * 4 + 1) * 3 + jj];
        acc += f.z * W[(k * 4 + 2) * 3 + jj];
        acc += f.w * W[(k * 4 + 3) * 3 + jj];
    }
    Yc[idx] = acc;
}

__global__ void coordcombine_kernel(const float* __restrict__ Yc, const float* __restrict__ bc,
                                    const int* __restrict__ rowptr, const int* __restrict__ dst,
                                    int V, float* __restrict__ out) {
    int idx = blockIdx.x * 256 + threadIdx.x;
    if (idx >= V * 3) return;
    int v = idx / 3, j = idx % 3;
    float val = Yc[(size_t)v * 6 + j] + bc[j];
    int e0 = rowptr[v], e1 = rowptr[v + 1];
    for (int e = e0; e < e1; ++e) val += Yc[(size_t)dst[e] * 6 + 3 + j];
    out[(size_t)v * 3 + j] = val;
}

// ---------------- unpool: verts midpoints + featpack hi/lo ------------------
__global__ void unpool_kernel(float* __restrict__ verts, const float* __restrict__ h,
                              const int* __restrict__ mid, int V, int Nm,
                              unsigned short* __restrict__ fphi, unsigned short* __restrict__ fplo) {
    int r = blockIdx.x;
    int t = threadIdx.x;  // 128
    if (r < V) {
        float v = h[(size_t)r * 128 + t];
        unsigned short hi, lo;
        f2hl(v, hi, lo);
        fphi[(size_t)r * 128 + t] = hi;
        fplo[(size_t)r * 128 + t] = lo;
    } else {
        int i = r - V;
        int a = mid[2 * i], b = mid[2 * i + 1];
        float v = 0.5f * (h[(size_t)a * 128 + t] + h[(size_t)b * 128 + t]);
        unsigned short hi, lo;
        f2hl(v, hi, lo);
        fphi[(size_t)r * 128 + t] = hi;
        fplo[(size_t)r * 128 + t] = lo;
        if (t < 3)
            verts[(size_t)r * 3 + t] = 0.5f * (verts[(size_t)a * 3 + t] + verts[(size_t)b * 3 + t]);
    }
}

// ---------------------------------------------------------------------------
extern "C" void kernel_launch(void* const* d_in, const int* in_sizes, int n_in,
                              void* d_out, int out_size, void* d_ws, size_t ws_size,
                              hipStream_t stream) {
    const float* f3 = (const float*)d_in[0];
    const float* f4 = (const float*)d_in[1];
    const float* f5 = (const float*)d_in[2];
    const float* verts0 = (const float*)d_in[3];
    const float* cam_c = (const float*)d_in[4];
    const float* cam_f = (const float*)d_in[5];
    const int* imgsz = (const int*)d_in[38];

    int V0 = in_sizes[3] / 3;
    int E[3] = {in_sizes[33] / 2, in_sizes[34] / 2, in_sizes[35] / 2};
    int Nm0 = in_sizes[36] / 2, Nm1 = in_sizes[37] / 2;
    int V1 = V0 + Nm0, V2 = V1 + Nm1;
    int Vs[3] = {V0, V1, V2};
    const int NPIXT = 3136 + 784 + 196;  // 4116
    const int GS = NPIXT * 256;          // per-stage G stride (floats)

    // ---- workspace (byte allocator, 256B aligned) ----
    char* wsp = (char*)d_ws;
    auto alloc = [&](size_t bytes) -> void* {
        void* p = (void*)wsp;
        wsp += (bytes + 255) & ~(size_t)255;
        return p;
    };
    unsigned short* ft0h = (unsigned short*)alloc((size_t)3136 * 256 * 2);
    unsigned short* ft0l = (unsigned short*)alloc((size_t)3136 * 256 * 2);
    unsigned short* ft1h = (unsigned short*)alloc((size_t)784 * 512 * 2);
    unsigned short* ft1l = (unsigned short*)alloc((size_t)784 * 512 * 2);
    unsigned short* ft2h = (unsigned short*)alloc((size_t)196 * 512 * 2);
    unsigned short* ft2l = (unsigned short*)alloc((size_t)196 * 512 * 2);
    unsigned short* Bg0h = (unsigned short*)alloc((size_t)768 * 256 * 2);
    unsigned short* Bg0l = (unsigned short*)alloc((size_t)768 * 256 * 2);
    unsigned short* Bg1h = (unsigned short*)alloc((size_t)768 * 512 * 2);
    unsigned short* Bg1l = (unsigned short*)alloc((size_t)768 * 512 * 2);
    unsigned short* Bg2h = (unsigned short*)alloc((size_t)768 * 512 * 2);
    unsigned short* Bg2l = (unsigned short*)alloc((size_t)768 * 512 * 2);
    float* Gbuf = (float*)alloc((size_t)3 * GS * 4);
    unsigned short* BtLhi = (unsigned short*)alloc((size_t)12 * 128 * 256 * 2);
    unsigned short* BtLlo = (unsigned short*)alloc((size_t)12 * 128 * 256 * 2);
    unsigned short* BtShi = (unsigned short*)alloc((size_t)256 * 128 * 2);
    unsigned short* BtSlo = (unsigned short*)alloc((size_t)256 * 128 * 2);
    float* Ybuf = (float*)alloc((size_t)V2 * 256 * 4);
    float* hA = (float*)alloc((size_t)V2 * 128 * 4);
    float* hB = (float*)alloc((size_t)V2 * 128 * 4);
    unsigned short* FPhi = (unsigned short*)alloc((size_t)V2 * 128 * 2);
    unsigned short* FPlo = (unsigned short*)alloc((size_t)V2 * 128 * 2);
    float* vertsbuf = (float*)alloc((size_t)V2 * 3 * 4);
    float* Yc = (float*)alloc((size_t)V2 * 6 * 4);
    int* sampi = (int*)alloc((size_t)V2 * 12 * 4);
    float* sampw = (float*)alloc((size_t)V2 * 12 * 4);
    int* rowptr = (int*)alloc(((size_t)V2 + 1) * 4);

    // ---- feature map transpose + hi/lo split ----
    transpose_hl<<<DIV_UP(256 * 56 * 56, 256), 256, 0, stream>>>(f3, ft0h, ft0l, 256, 56 * 56);
    transpose_hl<<<DIV_UP(512 * 28 * 28, 256), 256, 0, stream>>>(f4, ft1h, ft1l, 512, 28 * 28);
    transpose_hl<<<DIV_UP(512 * 14 * 14, 256), 256, 0, stream>>>(f5, ft2h, ft2l, 512, 14 * 14);

    const float* W0s_[3] = {(const float*)d_in[6], (const float*)d_in[15], (const float*)d_in[24]};
    const float* W1s_[3] = {(const float*)d_in[7], (const float*)d_in[16], (const float*)d_in[25]};

    // ---- G precompute (MFMA): G[s][pix][256] = ft_m @ W-slice ----
    pack_gb_bt<<<DIV_UP(768 * 256, 256), 256, 0, stream>>>(W0s_[0], W1s_[0], W0s_[1], W1s_[1],
                                                           W0s_[2], W1s_[2], Bg0h, Bg0l, 0, 256);
    pack_gb_bt<<<DIV_UP(768 * 512, 256), 256, 0, stream>>>(W0s_[0], W1s_[0], W0s_[1], W1s_[1],
                                                           W0s_[2], W1s_[2], Bg1h, Bg1l, 256, 512);
    pack_gb_bt<<<DIV_UP(768 * 512, 256), 256, 0, stream>>>(W0s_[0], W1s_[0], W0s_[1], W1s_[1],
                                                           W0s_[2], W1s_[2], Bg2h, Bg2l, 768, 512);
    {
        MArgs m = {};
        m.sstr = GS;
        m.Ahi = ft0h; m.Alo = ft0l; m.lda = 256;
        m.Bhi = Bg0h; m.Blo = Bg0l; m.K = 256;
        m.Y = Gbuf; m.V = 3136;
        dim3 g0(6, DIV_UP(3136, 64));
        mgemm<2><<<g0, 256, 0, stream>>>(m);
        m.Ahi = ft1h; m.Alo = ft1l; m.lda = 512;
        m.Bhi = Bg1h; m.Blo = Bg1l; m.K = 512;
        m.Y = Gbuf + (size_t)3136 * 256; m.V = 784;
        dim3 g1(6, DIV_UP(784, 64));
        mgemm<2><<<g1, 256, 0, stream>>>(m);
        m.Ahi = ft2h; m.Alo = ft2l; m.lda = 512;
        m.Bhi = Bg2h; m.Blo = Bg2l; m.K = 512;
        m.Y = Gbuf + (size_t)3920 * 256; m.V = 196;
        dim3 g2(6, DIV_UP(196, 64));
        mgemm<2><<<g2, 256, 0, stream>>>(m);
    }

    for (int si = 0; si < 3; ++si) {
        const float* Win0 = (const float*)d_in[6 + si * 9 + 0];
        const float* Win1 = (const float*)d_in[6 + si * 9 + 1];
        const float* bin = (const float*)d_in[6 + si * 9 + 2];
        const float* W0L = (const float*)d_in[6 + si * 9 + 3];
        const float* W1L = (const float*)d_in[6 + si * 9 + 4];
        const float* bs = (const float*)d_in[6 + si * 9 + 5];
        const float* Wc0 = (const float*)d_in[6 + si * 9 + 6];
        const float* Wc1 = (const float*)d_in[6 + si * 9 + 7];
        const float* bc = (const float*)d_in[6 + si * 9 + 8];
        const int* edges = (const int*)d_in[33 + si];
        int Ecur = E[si];
        const int* esrc = edges;
        const int* edst = edges + Ecur;
        int V = Vs[si];
        const float* vertsin = (si == 0) ? verts0 : vertsbuf;

        pack_lay_bt<<<12 * 128, 256, 0, stream>>>(W0L, W1L, BtLhi, BtLlo);
        if (si > 0) pack_sh_bt<<<128, 256, 0, stream>>>(Win0, Win1, BtShi, BtSlo);
        desc_kernel<<<DIV_UP(V, 256), 256, 0, stream>>>(vertsin, cam_c, cam_f, imgsz, V,
                                                        sampi, sampw);
        rowptr_kernel<<<DIV_UP(V + 1, 256), 256, 0, stream>>>(esrc, Ecur, V, rowptr);

        gather_kernel<<<V, 256, 0, stream>>>(Gbuf, GS, sampi, sampw, Ybuf, V, si, Win0, Win1,
                                             (si == 0) ? verts0 : nullptr);
        if (si > 0) {
            MArgs m = {};
            m.Ahi = FPhi; m.Alo = FPlo; m.lda = 128;
            m.Bhi = BtShi; m.Blo = BtSlo; m.K = 128;
            m.Y = Ybuf; m.V = V;
            dim3 grid(2, DIV_UP(V, 64));
            mgemm<0><<<grid, 256, 0, stream>>>(m);
        }
        combine_in<<<DIV_UP(V, 2), 256, 0, stream>>>(Ybuf, bin, rowptr, edst, hA, V);

        float* hcur = hA;
        float* hnext = hB;
        for (int ll = 0; ll < 12; ++ll) {
            LArgs a = {};
            a.h = hcur;
            a.Bhi = BtLhi + (size_t)ll * 32768;
            a.Blo = BtLlo + (size_t)ll * 32768;
            a.rowptr = rowptr; a.dst = edst;
            a.bias = bs + (size_t)ll * 128;
            a.hnext = hnext;
            a.V = V;
            lay_kernel<<<DIV_UP(V, 64), 256, 0, stream>>>(a);
            float* t = hcur; hcur = hnext; hnext = t;
        }

        coordgemm_kernel<<<DIV_UP(V * 6, 256), 256, 0, stream>>>(hcur, Wc0, Wc1, V, Yc);
        float* ctarget = (si == 2) ? (float*)d_out : vertsbuf;
        coordcombine_kernel<<<DIV_UP(V * 3, 256), 256, 0, stream>>>(Yc, bc, rowptr, edst, V,
                                                                    ctarget);
        if (si < 2) {
            const int* mid = (const int*)d_in[36 + si];
            int Nm = (si == 0) ? Nm0 : Nm1;
            unpool_kernel<<<V + Nm, 128, 0, stream>>>(vertsbuf, hcur, mid, V, Nm, FPhi, FPlo);
        }
    }
}

// Round 5
// 1417.796 us; speedup vs baseline: 2.3058x; 1.0661x over previous
//
#include <hip/hip_runtime.h>
#include <hip/hip_bf16.h>
#include <cstddef>
#include <cstdint>

#define DIV_UP(a, b) (((a) + (b) - 1) / (b))

typedef __attribute__((ext_vector_type(8))) short bf16x8v;
typedef __attribute__((ext_vector_type(4))) float f32x4v;

__device__ __forceinline__ unsigned short bf16_rn(float v) {
    unsigned int u = __float_as_uint(v);
    unsigned int r = (u + 0x7FFFu + ((u >> 16) & 1u)) >> 16;
    return (unsigned short)r;
}
__device__ __forceinline__ float bf16_f(unsigned short h) {
    return __uint_as_float(((unsigned int)h) << 16);
}
__device__ __forceinline__ void f2hl(float v, unsigned short& hi, unsigned short& lo) {
    hi = bf16_rn(v);
    float r = v - bf16_f(hi);
    lo = bf16_rn(r);
}
__device__ __forceinline__ int xcd_swz(int orig, int nwg) {
    int q = nwg >> 3, r = nwg & 7;
    int xcd = orig & 7, idx = orig >> 3;
    return (xcd < r ? xcd * (q + 1) : r * (q + 1) + (xcd - r) * q) + idx;
}

// ---------------- transpose (C,H,W) f32 -> (H*W, C) bf16 hi/lo --------------
__global__ void transpose_hl(const float* __restrict__ in, unsigned short* __restrict__ ohi,
                             unsigned short* __restrict__ olo, int C, int HW) {
    int idx = blockIdx.x * 256 + threadIdx.x;
    if (idx >= C * HW) return;
    int c = idx % C;
    int p = idx / C;
    float v = in[(size_t)c * HW + p];
    unsigned short hi, lo;
    f2hl(v, hi, lo);
    ohi[(size_t)p * C + c] = hi;
    olo[(size_t)p * C + c] = lo;
}

// ---------------- single fused weight-pack kernel ---------------------------
struct PackArgs {
    const float* Win0[3]; const float* Win1[3];   // [1408|1283][128]
    const float* W0L[3];  const float* W1L[3];    // [12][128][128]
    unsigned short *BtLhi[3], *BtLlo[3];          // [12][128][256]
    unsigned short *BtShi[2], *BtSlo[2];          // stages 1,2: [256][128]
    unsigned short *Bgh[3], *Bgl[3];              // [768][C] C=256,512,512
};

__global__ void pack_all(PackArgs p) {
    const int LAY1 = 12 * 128 * 256;           // 393216 per stage
    const int LAYT = 3 * LAY1;                 // 1179648
    const int SH1 = 256 * 128;                 // 32768 per stage
    const int SHT = 2 * SH1;
    const int GB0 = 768 * 256, GB1 = 768 * 512;
    int idx = blockIdx.x * 256 + threadIdx.x;
    float v;
    unsigned short* dh;
    unsigned short* dl;
    size_t o;
    if (idx < LAYT) {
        int st = idx / LAY1, r = idx % LAY1;
        int l = r >> 15, rr = r & 32767;
        int n = rr >> 8, k = rr & 255;
        v = (k < 128) ? p.W0L[st][(size_t)l * 16384 + k * 128 + n]
                      : p.W1L[st][(size_t)l * 16384 + (k - 128) * 128 + n];
        dh = p.BtLhi[st]; dl = p.BtLlo[st]; o = r;
    } else if (idx < LAYT + SHT) {
        int q = idx - LAYT;
        int st = q / SH1, rr = q % SH1;
        int n = rr >> 7, k = rr & 127;
        const float* w0 = p.Win0[st + 1];
        const float* w1 = p.Win1[st + 1];
        v = (n < 128) ? w0[(size_t)(1280 + k) * 128 + n]
                      : w1[(size_t)(1280 + k) * 128 + (n - 128)];
        dh = p.BtShi[st]; dl = p.BtSlo[st]; o = rr;
    } else {
        int q = idx - LAYT - SHT;
        int m, C, base;
        if (q < GB0) { m = 0; C = 256; base = 0; }
        else if (q < GB0 + GB1) { m = 1; C = 512; base = 256; q -= GB0; }
        else if (q < GB0 + 2 * GB1) { m = 2; C = 512; base = 768; q -= GB0 + GB1; }
        else return;
        int n = q / C, k = q % C;
        int s = n >> 8, j = n & 255;
        v = (j < 128) ? p.Win0[s][(size_t)(base + k) * 128 + j]
                      : p.Win1[s][(size_t)(base + k) * 128 + (j - 128)];
        dh = p.Bgh[m]; dl = p.Bgl[m]; o = q;
    }
    unsigned short hi, lo;
    f2hl(v, hi, lo);
    dh[o] = hi;
    dl[o] = lo;
}

// -------- per-vertex projection/bilerp descriptors + fixed-degree adj -------
__global__ void desc_adj_kernel(const float* __restrict__ verts,
                                const float* __restrict__ cam_c, const float* __restrict__ cam_f,
                                const int* __restrict__ imgsz, int V,
                                const int* __restrict__ src, const int* __restrict__ dst, int E,
                                int* __restrict__ sampi, float* __restrict__ sampw,
                                int* __restrict__ adj8) {
    int v = blockIdx.x * 256 + threadIdx.x;
    if (v >= V) return;
    float X = verts[3 * v + 0], Yy = verts[3 * v + 1], Z = verts[3 * v + 2];
    float cx = cam_c[0], cy = cam_c[1], fx = cam_f[0], fy = cam_f[1];
    const float tz = 0.8f;
    float pz = Z + tz;
    float px = (fx * X + cx * Z + tz * cx) / pz;
    float py = (fy * Yy + cy * Z + tz * cy) / pz;
    float is = (float)imgsz[0];
    const int Ss[3] = {56, 28, 14};
#pragma unroll
    for (int m = 0; m < 3; ++m) {
        int S = Ss[m];
        float dim = (float)S;
        float x = px * dim / is;
        float y = py * dim / is;
        float x1 = floorf(x), y1 = floorf(y);
        float x2 = x1 + 1.0f, y2 = y1 + 1.0f;
        float smax = (float)(S - 1);
        int xi1 = (int)fminf(fmaxf(x1, 0.0f), smax);
        int xi2 = (int)fminf(fmaxf(x2, 0.0f), smax);
        int yi1 = (int)fminf(fmaxf(y1, 0.0f), smax);
        int yi2 = (int)fminf(fmaxf(y2, 0.0f), smax);
        int b = v * 12 + m * 4;
        sampi[b + 0] = xi1 * S + yi1;
        sampi[b + 1] = xi1 * S + yi2;
        sampi[b + 2] = xi2 * S + yi1;
        sampi[b + 3] = xi2 * S + yi2;
        sampw[b + 0] = (x2 - x) * (y2 - y);
        sampw[b + 1] = (x2 - x) * (y - y1);
        sampw[b + 2] = (x - x1) * (y2 - y);
        sampw[b + 3] = (x - x1) * (y - y1);
    }
    // fixed-degree adjacency via two binary searches on sorted src
    int lo = 0, hi = E;
    while (lo < hi) { int m = (lo + hi) >> 1; if (src[m] < v) lo = m + 1; else hi = m; }
    int e0 = lo;
    hi = E;
    while (lo < hi) { int m = (lo + hi) >> 1; if (src[m] < v + 1) lo = m + 1; else hi = m; }
    int e1 = lo;
    int* ap = adj8 + (size_t)v * 8;
#pragma unroll
    for (int i = 0; i < 8; ++i) {
        int e = e0 + i;
        ap[i] = (e < e1) ? dst[e] : -1;
    }
}

// ---------------- MFMA bf16x3 GEMM ------------------------------------------
// EPI 2: G precompute scatter-store; EPI 3: plain store Y[row*256+col].
struct MArgs {
    const unsigned short *Ahi, *Alo; int lda;
    const unsigned short *Bhi, *Blo; int K;  // Bt row-major [N][K]
    float* Y;
    int sstr;
    int V;
};

template <int EPI>
__global__ __launch_bounds__(256) void mgemm(MArgs g) {
    __shared__ unsigned short As_hi[64][40], As_lo[64][40];
    __shared__ unsigned short Bs_hi[128][40], Bs_lo[128][40];
    int tid = threadIdx.x;
    int row0 = blockIdx.y * 64;
    int col0 = blockIdx.x * 128;
    int l = tid & 63, wid = tid >> 6;
    int wr = wid & 1, wc = wid >> 1;
    int lw = l & 15, gg = l >> 4;
    f32x4v acc[2][4];
#pragma unroll
    for (int i = 0; i < 2; ++i)
#pragma unroll
        for (int j = 0; j < 4; ++j) acc[i][j] = (f32x4v){0.f, 0.f, 0.f, 0.f};

    int arow = tid >> 2, akoff = (tid & 3) * 8;
    for (int k0 = 0; k0 < g.K; k0 += 32) {
        __syncthreads();
        {
            int grow = row0 + arow;
            uint4 zh = make_uint4(0, 0, 0, 0), zl = make_uint4(0, 0, 0, 0);
            if (grow < g.V) {
                zh = *(const uint4*)(g.Ahi + (size_t)grow * g.lda + k0 + akoff);
                zl = *(const uint4*)(g.Alo + (size_t)grow * g.lda + k0 + akoff);
            }
            *(uint4*)&As_hi[arow][akoff] = zh;
            *(uint4*)&As_lo[arow][akoff] = zl;
        }
#pragma unroll
        for (int it = 0; it < 2; ++it) {
            int q = tid + it * 256;
            int n = q >> 2, koff = (q & 3) * 8;
            *(uint4*)&Bs_hi[n][koff] = *(const uint4*)(g.Bhi + (size_t)(col0 + n) * g.K + k0 + koff);
            *(uint4*)&Bs_lo[n][koff] = *(const uint4*)(g.Blo + (size_t)(col0 + n) * g.K + k0 + koff);
        }
        __syncthreads();
        bf16x8v ah[2], al[2], bh[4], bl[4];
#pragma unroll
        for (int mt = 0; mt < 2; ++mt) {
            int r = wr * 32 + mt * 16 + lw;
            ah[mt] = *(const bf16x8v*)&As_hi[r][gg * 8];
            al[mt] = *(const bf16x8v*)&As_lo[r][gg * 8];
        }
#pragma unroll
        for (int nt = 0; nt < 4; ++nt) {
            int c = wc * 64 + nt * 16 + lw;
            bh[nt] = *(const bf16x8v*)&Bs_hi[c][gg * 8];
            bl[nt] = *(const bf16x8v*)&Bs_lo[c][gg * 8];
        }
#pragma unroll
        for (int mt = 0; mt < 2; ++mt)
#pragma unroll
            for (int nt = 0; nt < 4; ++nt) {
                acc[mt][nt] = __builtin_amdgcn_mfma_f32_16x16x32_bf16(ah[mt], bh[nt], acc[mt][nt], 0, 0, 0);
                acc[mt][nt] = __builtin_amdgcn_mfma_f32_16x16x32_bf16(ah[mt], bl[nt], acc[mt][nt], 0, 0, 0);
                acc[mt][nt] = __builtin_amdgcn_mfma_f32_16x16x32_bf16(al[mt], bh[nt], acc[mt][nt], 0, 0, 0);
            }
    }
#pragma unroll
    for (int mt = 0; mt < 2; ++mt)
#pragma unroll
        for (int nt = 0; nt < 4; ++nt) {
            int colg = wc * 64 + nt * 16 + lw;
#pragma unroll
            for (int r = 0; r < 4; ++r) {
                int rowg = row0 + wr * 32 + mt * 16 + gg * 4 + r;
                if (rowg >= g.V) continue;
                float v = acc[mt][nt][r];
                if (EPI == 3) {
                    g.Y[(size_t)rowg * 256 + col0 + colg] = v;
                } else {
                    int cg = col0 + colg;
                    g.Y[(size_t)(cg >> 8) * g.sstr + (size_t)rowg * 256 + (cg & 255)] = v;
                }
            }
        }
}

// ---------------- input perceptual gather (adds to pre-stored Ybuf) ---------
__global__ void gather_kernel(const float* __restrict__ G, int sstr,
                              const int* __restrict__ sampi, const float* __restrict__ sampw,
                              float* __restrict__ Yb, int V, int stage,
                              const float* __restrict__ Win0, const float* __restrict__ Win1,
                              const float* __restrict__ shape) {
    int v = xcd_swz(blockIdx.x, gridDim.x);
    if (v >= V) return;
    int j = threadIdx.x;
    const float* Gs = G + (size_t)stage * sstr;
    int b = v * 12;
    float acc = (stage == 0) ? 0.0f : Yb[(size_t)v * 256 + j];
#pragma unroll
    for (int s = 0; s < 4; ++s)
        acc += sampw[b + s] * Gs[(size_t)sampi[b + s] * 256 + j];
#pragma unroll
    for (int s = 0; s < 4; ++s)
        acc += sampw[b + 4 + s] * Gs[(size_t)(3136 + sampi[b + 4 + s]) * 256 + j];
#pragma unroll
    for (int s = 0; s < 4; ++s)
        acc += sampw[b + 8 + s] * Gs[(size_t)(3920 + sampi[b + 8 + s]) * 256 + j];
    if (stage == 0) {
#pragma unroll
        for (int k = 0; k < 3; ++k) {
            float w = shape[v * 3 + k];
            float wv = (j < 128) ? Win0[(size_t)(1280 + k) * 128 + j]
                                 : Win1[(size_t)(1280 + k) * 128 + (j - 128)];
            acc += w * wv;
        }
    }
    Yb[(size_t)v * 256 + j] = acc;
}

// ---------------- input-layer combine: h = relu(Y0 + agg(Y1) + b) ----------
__global__ __launch_bounds__(256) void combine_in(
    const float* __restrict__ Y, const float* __restrict__ bias,
    const int* __restrict__ adj8,
    float* __restrict__ hout, int V) {
    int bid = xcd_swz(blockIdx.x, gridDim.x);
    int v = bid * 2 + (threadIdx.x >> 7);
    int d = threadIdx.x & 127;
    if (v >= V) return;
    float val = Y[(size_t)v * 256 + d] + bias[d];
    const int* ap = adj8 + (size_t)v * 8;
    int n[6];
#pragma unroll
    for (int i = 0; i < 6; ++i) n[i] = ap[i];
#pragma unroll
    for (int i = 0; i < 6; ++i)
        if (n[i] >= 0) val += Y[(size_t)n[i] * 256 + 128 + d];
    val = fmaxf(val, 0.0f);
    hout[(size_t)v * 128 + d] = val;
}

// ---------------- fused resnet layer: adj gather + GEMM + epilogue ----------
struct LArgs {
    const float* h;                                   // [V][128] f32
    const unsigned short *Bhi, *Blo;                  // [128][256]
    const int* adj8;
    const float* bias;
    float* hnext;
    int V;
};

__global__ __launch_bounds__(256) void lay_kernel(LArgs g) {
    __shared__ unsigned short As_hi[64][40], As_lo[64][40];
    __shared__ unsigned short Bs_hi[128][40], Bs_lo[128][40];
    int tid = threadIdx.x;
    int row0 = xcd_swz(blockIdx.x, gridDim.x) * 64;

    int l = tid & 63, wid = tid >> 6;
    int wr = wid & 1, wc = wid >> 1;
    int lw = l & 15, gg = l >> 4;
    int arow = tid >> 2;
    int aq = tid & 3;           // k-slice owner: cols aq*32..aq*32+31
    int grow = row0 + arow;

    f32x4v acc[2][4];
#pragma unroll
    for (int i = 0; i < 2; ++i)
#pragma unroll
        for (int j = 0; j < 4; ++j) acc[i][j] = (f32x4v){0.f, 0.f, 0.f, 0.f};

    float vals[32];

    auto mfma_step = [&](int ks, int kglob0) {
        uint4 b0h, b1h, b0l, b1l;
        {
            int n0 = tid >> 2, koff = (tid & 3) * 8;
            b0h = *(const uint4*)(g.Bhi + (size_t)n0 * 256 + kglob0 + koff);
            b0l = *(const uint4*)(g.Blo + (size_t)n0 * 256 + kglob0 + koff);
            int n1 = n0 + 64;
            b1h = *(const uint4*)(g.Bhi + (size_t)n1 * 256 + kglob0 + koff);
            b1l = *(const uint4*)(g.Blo + (size_t)n1 * 256 + kglob0 + koff);
        }
        if (aq == ks) {
            unsigned short hh[8], ll[8];
#pragma unroll
            for (int c = 0; c < 4; ++c) {
#pragma unroll
                for (int i = 0; i < 8; ++i) f2hl(vals[c * 8 + i], hh[i], ll[i]);
                *(uint4*)&As_hi[arow][c * 8] = *(uint4*)hh;
                *(uint4*)&As_lo[arow][c * 8] = *(uint4*)ll;
            }
        }
        {
            int n0 = tid >> 2, koff = (tid & 3) * 8;
            *(uint4*)&Bs_hi[n0][koff] = b0h;
            *(uint4*)&Bs_lo[n0][koff] = b0l;
            *(uint4*)&Bs_hi[n0 + 64][koff] = b1h;
            *(uint4*)&Bs_lo[n0 + 64][koff] = b1l;
        }
        __syncthreads();
        bf16x8v ah[2], al[2], bh[4], bl[4];
#pragma unroll
        for (int mt = 0; mt < 2; ++mt) {
            int r = wr * 32 + mt * 16 + lw;
            ah[mt] = *(const bf16x8v*)&As_hi[r][gg * 8];
            al[mt] = *(const bf16x8v*)&As_lo[r][gg * 8];
        }
#pragma unroll
        for (int nt = 0; nt < 4; ++nt) {
            int c = wc * 64 + nt * 16 + lw;
            bh[nt] = *(const bf16x8v*)&Bs_hi[c][gg * 8];
            bl[nt] = *(const bf16x8v*)&Bs_lo[c][gg * 8];
        }
#pragma unroll
        for (int mt = 0; mt < 2; ++mt)
#pragma unroll
            for (int nt = 0; nt < 4; ++nt) {
                acc[mt][nt] = __builtin_amdgcn_mfma_f32_16x16x32_bf16(ah[mt], bh[nt], acc[mt][nt], 0, 0, 0);
                acc[mt][nt] = __builtin_amdgcn_mfma_f32_16x16x32_bf16(ah[mt], bl[nt], acc[mt][nt], 0, 0, 0);
                acc[mt][nt] = __builtin_amdgcn_mfma_f32_16x16x32_bf16(al[mt], bh[nt], acc[mt][nt], 0, 0, 0);
            }
        __syncthreads();
    };

    // ---- own half (k-global 0..127): h row slice in regs ----
    if (grow < g.V) {
        const float* hp = g.h + (size_t)grow * 128 + aq * 32;
#pragma unroll
        for (int c = 0; c < 8; ++c) {
            float4 f = *(const float4*)(hp + c * 4);
            vals[c * 4 + 0] = f.x;
            vals[c * 4 + 1] = f.y;
            vals[c * 4 + 2] = f.z;
            vals[c * 4 + 3] = f.w;
        }
    } else {
#pragma unroll
        for (int i = 0; i < 32; ++i) vals[i] = 0.0f;
    }
    for (int ks = 0; ks < 4; ++ks) mfma_step(ks, ks * 32);

    // ---- fixed-degree aggregation (k-global 128..255): 6 independent loads -
#pragma unroll
    for (int i = 0; i < 32; ++i) vals[i] = 0.0f;
    if (grow < g.V) {
        const int* ap = g.adj8 + (size_t)grow * 8;
        int n[6];
#pragma unroll
        for (int i = 0; i < 6; ++i) n[i] = ap[i];
#pragma unroll
        for (int i = 0; i < 6; ++i) {
            if (n[i] >= 0) {
                const float* hp = g.h + (size_t)n[i] * 128 + aq * 32;
#pragma unroll
                for (int c = 0; c < 8; ++c) {
                    float4 f = *(const float4*)(hp + c * 4);
                    vals[c * 4 + 0] += f.x;
                    vals[c * 4 + 1] += f.y;
                    vals[c * 4 + 2] += f.z;
                    vals[c * 4 + 3] += f.w;
                }
            }
        }
    }
    for (int ks = 0; ks < 4; ++ks) mfma_step(ks, 128 + ks * 32);

    // ---- epilogue: hnext = relu(acc + bias) + h ----
#pragma unroll
    for (int mt = 0; mt < 2; ++mt)
#pragma unroll
        for (int nt = 0; nt < 4; ++nt) {
            int colg = wc * 64 + nt * 16 + lw;
            float bv = g.bias[colg];
#pragma unroll
            for (int r = 0; r < 4; ++r) {
                int rowg = row0 + wr * 32 + mt * 16 + gg * 4 + r;
                if (rowg >= g.V) continue;
                float v = acc[mt][nt][r] + bv;
                v = fmaxf(v, 0.0f);
                v += g.h[(size_t)rowg * 128 + colg];
                g.hnext[(size_t)rowg * 128 + colg] = v;
            }
        }
}

// ---------------- coord head ------------------------------------------------
__global__ void coordgemm_kernel(const float* __restrict__ h,
                                 const float* __restrict__ Wc0, const float* __restrict__ Wc1,
                                 int V, float* __restrict__ Yc) {
    int idx = blockIdx.x * 256 + threadIdx.x;
    if (idx >= V * 6) return;
    int v = idx / 6, j = idx % 6;
    const float* W = (j < 3) ? Wc0 : Wc1;
    int jj = (j < 3) ? j : j - 3;
    const float* hp = h + (size_t)v * 128;
    float acc = 0.0f;
#pragma unroll
    for (int k = 0; k < 32; ++k) {
        float4 f = *(const float4*)(hp + k * 4);
        acc += f.x * W[(k * 4 + 0) * 3 + jj];
        acc += f.y * W[(k * 4 + 1) * 3 + jj];
        acc += f.z * W[(k * 4 + 2) * 3 + jj];
        acc += f.w * W[(k * 4 + 3) * 3 + jj];
    }
    Yc[idx] = acc;
}

__global__ void coordcombine_kernel(const float* __restrict__ Yc, const float* __restrict__ bc,
                                    const int* __restrict__ adj8,
                                    int V, float* __restrict__ out) {
    int idx = blockIdx.x * 256 + threadIdx.x;
    if (idx >= V * 3) return;
    int v = idx / 3, j = idx % 3;
    float val = Yc[(size_t)v * 6 + j] + bc[j];
    const int* ap = adj8 + (size_t)v * 8;
    int n[6];
#pragma unroll
    for (int i = 0; i < 6; ++i) n[i] = ap[i];
#pragma unroll
    for (int i = 0; i < 6; ++i)
        if (n[i] >= 0) val += Yc[(size_t)n[i] * 6 + 3 + j];
    out[(size_t)v * 3 + j] = val;
}

// ---------------- unpool: verts midpoints + featpack hi/lo ------------------
__global__ void unpool_kernel(float* __restrict__ verts, const float* __restrict__ h,
                              const int* __restrict__ mid, int V, int Nm,
                              unsigned short* __restrict__ fphi, unsigned short* __restrict__ fplo) {
    int r = blockIdx.x;
    int t = threadIdx.x;  // 128
    if (r < V) {
        float v = h[(size_t)r * 128 + t];
        unsigned short hi, lo;
        f2hl(v, hi, lo);
        fphi[(size_t)r * 128 + t] = hi;
        fplo[(size_t)r * 128 + t] = lo;
    } else {
        int i = r - V;
        int a = mid[2 * i], b = mid[2 * i + 1];
        float v = 0.5f * (h[(size_t)a * 128 + t] + h[(size_t)b * 128 + t]);
        unsigned short hi, lo;
        f2hl(v, hi, lo);
        fphi[(size_t)r * 128 + t] = hi;
        fplo[(size_t)r * 128 + t] = lo;
        if (t < 3)
            verts[(size_t)r * 3 + t] = 0.5f * (verts[(size_t)a * 3 + t] + verts[(size_t)b * 3 + t]);
    }
}

// ---------------------------------------------------------------------------
extern "C" void kernel_launch(void* const* d_in, const int* in_sizes, int n_in,
                              void* d_out, int out_size, void* d_ws, size_t ws_size,
                              hipStream_t stream) {
    const float* f3 = (const float*)d_in[0];
    const float* f4 = (const float*)d_in[1];
    const float* f5 = (const float*)d_in[2];
    const float* verts0 = (const float*)d_in[3];
    const float* cam_c = (const float*)d_in[4];
    const float* cam_f = (const float*)d_in[5];
    const int* imgsz = (const int*)d_in[38];

    int V0 = in_sizes[3] / 3;
    int E[3] = {in_sizes[33] / 2, in_sizes[34] / 2, in_sizes[35] / 2};
    int Nm0 = in_sizes[36] / 2, Nm1 = in_sizes[37] / 2;
    int V1 = V0 + Nm0, V2 = V1 + Nm1;
    int Vs[3] = {V0, V1, V2};
    const int NPIXT = 3136 + 784 + 196;  // 4116
    const int GS = NPIXT * 256;          // per-stage G stride (floats)

    // ---- workspace (byte allocator, 256B aligned) ----
    char* wsp = (char*)d_ws;
    auto alloc = [&](size_t bytes) -> void* {
        void* p = (void*)wsp;
        wsp += (bytes + 255) & ~(size_t)255;
        return p;
    };
    unsigned short* ft0h = (unsigned short*)alloc((size_t)3136 * 256 * 2);
    unsigned short* ft0l = (unsigned short*)alloc((size_t)3136 * 256 * 2);
    unsigned short* ft1h = (unsigned short*)alloc((size_t)784 * 512 * 2);
    unsigned short* ft1l = (unsigned short*)alloc((size_t)784 * 512 * 2);
    unsigned short* ft2h = (unsigned short*)alloc((size_t)196 * 512 * 2);
    unsigned short* ft2l = (unsigned short*)alloc((size_t)196 * 512 * 2);
    unsigned short* Bg0h = (unsigned short*)alloc((size_t)768 * 256 * 2);
    unsigned short* Bg0l = (unsigned short*)alloc((size_t)768 * 256 * 2);
    unsigned short* Bg1h = (unsigned short*)alloc((size_t)768 * 512 * 2);
    unsigned short* Bg1l = (unsigned short*)alloc((size_t)768 * 512 * 2);
    unsigned short* Bg2h = (unsigned short*)alloc((size_t)768 * 512 * 2);
    unsigned short* Bg2l = (unsigned short*)alloc((size_t)768 * 512 * 2);
    float* Gbuf = (float*)alloc((size_t)3 * GS * 4);
    unsigned short* BtLhi[3];
    unsigned short* BtLlo[3];
    for (int s = 0; s < 3; ++s) {
        BtLhi[s] = (unsigned short*)alloc((size_t)12 * 128 * 256 * 2);
        BtLlo[s] = (unsigned short*)alloc((size_t)12 * 128 * 256 * 2);
    }
    unsigned short* BtShi[2];
    unsigned short* BtSlo[2];
    for (int s = 0; s < 2; ++s) {
        BtShi[s] = (unsigned short*)alloc((size_t)256 * 128 * 2);
        BtSlo[s] = (unsigned short*)alloc((size_t)256 * 128 * 2);
    }
    float* Ybuf = (float*)alloc((size_t)V2 * 256 * 4);
    float* hA = (float*)alloc((size_t)V2 * 128 * 4);
    float* hB = (float*)alloc((size_t)V2 * 128 * 4);
    unsigned short* FPhi = (unsigned short*)alloc((size_t)V2 * 128 * 2);
    unsigned short* FPlo = (unsigned short*)alloc((size_t)V2 * 128 * 2);
    float* vertsbuf = (float*)alloc((size_t)V2 * 3 * 4);
    float* Yc = (float*)alloc((size_t)V2 * 6 * 4);
    int* sampi = (int*)alloc((size_t)V2 * 12 * 4);
    float* sampw = (float*)alloc((size_t)V2 * 12 * 4);
    int* adj8 = (int*)alloc((size_t)V2 * 8 * 4);

    // ---- feature map transpose + hi/lo split ----
    transpose_hl<<<DIV_UP(256 * 56 * 56, 256), 256, 0, stream>>>(f3, ft0h, ft0l, 256, 56 * 56);
    transpose_hl<<<DIV_UP(512 * 28 * 28, 256), 256, 0, stream>>>(f4, ft1h, ft1l, 512, 28 * 28);
    transpose_hl<<<DIV_UP(512 * 14 * 14, 256), 256, 0, stream>>>(f5, ft2h, ft2l, 512, 14 * 14);

    // ---- single fused weight pack ----
    {
        PackArgs p;
        for (int s = 0; s < 3; ++s) {
            p.Win0[s] = (const float*)d_in[6 + s * 9 + 0];
            p.Win1[s] = (const float*)d_in[6 + s * 9 + 1];
            p.W0L[s] = (const float*)d_in[6 + s * 9 + 3];
            p.W1L[s] = (const float*)d_in[6 + s * 9 + 4];
            p.BtLhi[s] = BtLhi[s]; p.BtLlo[s] = BtLlo[s];
        }
        p.BtShi[0] = BtShi[0]; p.BtSlo[0] = BtSlo[0];
        p.BtShi[1] = BtShi[1]; p.BtSlo[1] = BtSlo[1];
        p.Bgh[0] = Bg0h; p.Bgl[0] = Bg0l;
        p.Bgh[1] = Bg1h; p.Bgl[1] = Bg1l;
        p.Bgh[2] = Bg2h; p.Bgl[2] = Bg2l;
        int total = 3 * 12 * 128 * 256 + 2 * 256 * 128 + 768 * 256 + 2 * 768 * 512;
        pack_all<<<DIV_UP(total, 256), 256, 0, stream>>>(p);
    }

    // ---- G precompute (MFMA): G[s][pix][256] = ft_m @ W-slice ----
    {
        MArgs m = {};
        m.sstr = GS;
        m.Ahi = ft0h; m.Alo = ft0l; m.lda = 256;
        m.Bhi = Bg0h; m.Blo = Bg0l; m.K = 256;
        m.Y = Gbuf; m.V = 3136;
        dim3 g0(6, DIV_UP(3136, 64));
        mgemm<2><<<g0, 256, 0, stream>>>(m);
        m.Ahi = ft1h; m.Alo = ft1l; m.lda = 512;
        m.Bhi = Bg1h; m.Blo = Bg1l; m.K = 512;
        m.Y = Gbuf + (size_t)3136 * 256; m.V = 784;
        dim3 g1(6, DIV_UP(784, 64));
        mgemm<2><<<g1, 256, 0, stream>>>(m);
        m.Ahi = ft2h; m.Alo = ft2l; m.lda = 512;
        m.Bhi = Bg2h; m.Blo = Bg2l; m.K = 512;
        m.Y = Gbuf + (size_t)3920 * 256; m.V = 196;
        dim3 g2(6, DIV_UP(196, 64));
        mgemm<2><<<g2, 256, 0, stream>>>(m);
    }

    for (int si = 0; si < 3; ++si) {
        const float* Win0 = (const float*)d_in[6 + si * 9 + 0];
        const float* Win1 = (const float*)d_in[6 + si * 9 + 1];
        const float* bin = (const float*)d_in[6 + si * 9 + 2];
        const float* bs = (const float*)d_in[6 + si * 9 + 5];
        const float* Wc0 = (const float*)d_in[6 + si * 9 + 6];
        const float* Wc1 = (const float*)d_in[6 + si * 9 + 7];
        const float* bc = (const float*)d_in[6 + si * 9 + 8];
        const int* edges = (const int*)d_in[33 + si];
        int Ecur = E[si];
        const int* esrc = edges;
        const int* edst = edges + Ecur;
        int V = Vs[si];
        const float* vertsin = (si == 0) ? verts0 : vertsbuf;

        desc_adj_kernel<<<DIV_UP(V, 256), 256, 0, stream>>>(vertsin, cam_c, cam_f, imgsz, V,
                                                            esrc, edst, Ecur, sampi, sampw, adj8);
        // shape GEMM first (pure store), then gather adds perceptual part
        if (si > 0) {
            MArgs m = {};
            m.Ahi = FPhi; m.Alo = FPlo; m.lda = 128;
            m.Bhi = BtShi[si - 1]; m.Blo = BtSlo[si - 1]; m.K = 128;
            m.Y = Ybuf; m.V = V;
            dim3 grid(2, DIV_UP(V, 64));
            mgemm<3><<<grid, 256, 0, stream>>>(m);
        }
        gather_kernel<<<V, 256, 0, stream>>>(Gbuf, GS, sampi, sampw, Ybuf, V, si, Win0, Win1,
                                             (si == 0) ? verts0 : nullptr);
        combine_in<<<DIV_UP(V, 2), 256, 0, stream>>>(Ybuf, bin, adj8, hA, V);

        float* hcur = hA;
        float* hnext = hB;
        for (int ll = 0; ll < 12; ++ll) {
            LArgs a = {};
            a.h = hcur;
            a.Bhi = BtLhi[si] + (size_t)ll * 32768;
            a.Blo = BtLlo[si] + (size_t)ll * 32768;
            a.adj8 = adj8;
            a.bias = bs + (size_t)ll * 128;
            a.hnext = hnext;
            a.V = V;
            lay_kernel<<<DIV_UP(V, 64), 256, 0, stream>>>(a);
            float* t = hcur; hcur = hnext; hnext = t;
        }

        coordgemm_kernel<<<DIV_UP(V * 6, 256), 256, 0, stream>>>(hcur, Wc0, Wc1, V, Yc);
        float* ctarget = (si == 2) ? (float*)d_out : vertsbuf;
        coordcombine_kernel<<<DIV_UP(V * 3, 256), 256, 0, stream>>>(Yc, bc, adj8, V, ctarget);
        if (si < 2) {
            const int* mid = (const int*)d_in[36 + si];
            int Nm = (si == 0) ? Nm0 : Nm1;
            unpool_kernel<<<V + Nm, 128, 0, stream>>>(vertsbuf, hcur, mid, V, Nm, FPhi, FPlo);
        }
    }
}